// Round 1
// baseline (10234.267 us; speedup 1.0000x reference)
//
#include <hip/hip_runtime.h>

#define BT (16 * 8192)
#define NB 5

// ---------- helpers ----------
__device__ __forceinline__ void atomicMaxF(float* addr, float v) {
    if (v >= 0.0f) atomicMax((int*)addr, __float_as_int(v));
    else           atomicMin((unsigned int*)addr, __float_as_uint(v));
}

__device__ __forceinline__ void fma4(float4& acc, float a, const float4& w) {
    acc.x = fmaf(a, w.x, acc.x);
    acc.y = fmaf(a, w.y, acc.y);
    acc.z = fmaf(a, w.z, acc.z);
    acc.w = fmaf(a, w.w, acc.w);
}

// ---------- plane indices (bitwise-identical op sequence to reference) ----------
__global__ void k_idx(const float* __restrict__ p, int* __restrict__ idx) {
    int r = blockIdx.x * 256 + threadIdx.x;
    if (r >= BT) return;
    float p0 = p[3 * r + 0], p1 = p[3 * r + 1], p2 = p[3 * r + 2];
    const float DEN = (float)(1.0 + 0.1 + 1e-3);
    const float HI  = (float)(1.0 - 1e-5);
    int b = r >> 13;  // T = 8192
    // normalize: (p/8)/DEN + 0.5, clip[0,HI], *64, trunc
    float x0 = fminf(fmaxf((p0 / 8.0f) / DEN + 0.5f, 0.0f), HI);
    float x1 = fminf(fmaxf((p1 / 8.0f) / DEN + 0.5f, 0.0f), HI);
    float x2 = fminf(fmaxf((p2 / 8.0f) / DEN + 0.5f, 0.0f), HI);
    int i0 = (int)(x0 * 64.0f);
    int i1 = (int)(x1 * 64.0f);
    int i2 = (int)(x2 * 64.0f);
    int base = b << 12;  // b * 4096
    idx[r]          = base + i0 + (i2 << 6);  // xz: (0,2)
    idx[BT + r]     = base + i0 + (i1 << 6);  // xy: (0,1)
    idx[2 * BT + r] = base + i1 + (i2 << 6);  // yz: (1,2)
}

// ---------- batch mean of net (B,T,128) -> (B,128), scaled by 1/T ----------
__global__ void k_mean(const float* __restrict__ net, float* __restrict__ mean) {
    __shared__ float red[256];
    int t = threadIdx.x;
    int base = blockIdx.x * 256;            // row base (rows of net)
    int c = t & 127, half = t >> 7;
    float s = 0.0f;
    for (int i = 0; i < 128; ++i) {
        int r = base + half + (i << 1);
        s += net[(size_t)r * 128 + c];
    }
    red[t] = s;
    __syncthreads();
    if (t < 128) {
        int b = blockIdx.x >> 5;            // 32 blocks per batch
        atomicAdd(mean + (b << 7) + t, (red[t] + red[t + 128]) * (1.0f / 8192.0f));
    }
}

// ---------- scatter max: net -> seg (seg pre-memset to 0xFF == -NaN sentinel) ----------
__global__ void k_scatter_max(const float* __restrict__ net, const int* __restrict__ idx,
                              float* __restrict__ seg) {
    int tid = blockIdx.x * 256 + threadIdx.x;
    int r = tid >> 5, c4 = (tid & 31) << 2;
    int cell = idx[r];
    float4 v = *(const float4*)(net + (size_t)r * 128 + c4);
    float* d = seg + (size_t)cell * 128 + c4;
    atomicMaxF(d + 0, v.x);
    atomicMaxF(d + 1, v.y);
    atomicMaxF(d + 2, v.z);
    atomicMaxF(d + 3, v.w);
}

// ---------- gather pooled (+)= seg[idx] ----------
template <bool FIRST>
__global__ void k_gather(const int* __restrict__ idx, const float* __restrict__ seg,
                         float* __restrict__ pooled) {
    int tid = blockIdx.x * 256 + threadIdx.x;
    int r = tid >> 5, c4 = (tid & 31) << 2;
    int cell = idx[r];
    float4 v = *(const float4*)(seg + (size_t)cell * 128 + c4);
    float4* o = (float4*)(pooled + (size_t)r * 128 + c4);
    if (FIRST) {
        *o = v;
    } else {
        float4 u = *o;
        u.x += v.x; u.y += v.y; u.z += v.z; u.w += v.w;
        *o = u;
    }
}

// ---------- tiled f32 GEMM accumulate: acc += (relu?)(A_lds) @ W ----------
// A tile: 32 rows x K (lds), W: (K,128) global, staged in 32-row chunks into wT.
template <bool RELU_A>
__device__ __forceinline__ void gemm_accum(const float* __restrict__ aS, int lda, int K,
                                           const float* __restrict__ Wg, float* __restrict__ wT,
                                           int t, int r0, int c0, float4 acc[4]) {
    for (int kt = 0; kt < K; kt += 32) {
        __syncthreads();  // protect wT (and aS/hT staging on first entry)
        const float4* Wg4 = (const float4*)(Wg + (size_t)kt * 128);
        float4* wT4 = (float4*)wT;
#pragma unroll
        for (int i = 0; i < 4; ++i) wT4[t + 256 * i] = Wg4[t + 256 * i];
        __syncthreads();
#pragma unroll
        for (int kk = 0; kk < 32; kk += 4) {
            float4 w[4];
#pragma unroll
            for (int j = 0; j < 4; ++j) w[j] = *(const float4*)(wT + (kk + j) * 128 + c0);
#pragma unroll
            for (int i = 0; i < 4; ++i) {
                float4 a = *(const float4*)(aS + (r0 + i) * lda + kt + kk);
                float x0 = RELU_A ? fmaxf(a.x, 0.0f) : a.x;
                float x1 = RELU_A ? fmaxf(a.y, 0.0f) : a.y;
                float x2 = RELU_A ? fmaxf(a.z, 0.0f) : a.z;
                float x3 = RELU_A ? fmaxf(a.w, 0.0f) : a.w;
                fma4(acc[i], x0, w[0]);
                fma4(acc[i], x1, w[1]);
                fma4(acc[i], x2, w[2]);
                fma4(acc[i], x3, w[3]);
            }
        }
    }
}

// ---------- fused resblock ----------
// MODE 0: A = p @ fc_pos_W + fc_pos_b (computed in staging); src0 = p (BT,3)
// MODE 1: A = concat(net, pooled, mean_bcast); src0 = net (BT,128)
// out = A @ Ws + relu(relu(A) @ W0 + b0) @ W1 + b1
template <int MODE>
__global__ __launch_bounds__(256, 2) void k_resblock(
    const float* __restrict__ src0, const float* __restrict__ pooled,
    const float* __restrict__ mean, const float* __restrict__ Wp,
    const float* __restrict__ bp, const float* __restrict__ W0,
    const float* __restrict__ b0, const float* __restrict__ W1,
    const float* __restrict__ b1, const float* __restrict__ Ws,
    float* __restrict__ out) {
    __shared__ float aT[32 * 384];  // 48 KB
    __shared__ float hT[32 * 128];  // 16 KB
    __shared__ float wT[32 * 128];  // 16 KB  -> 80 KB total, 2 blocks/CU
    const int t = threadIdx.x;
    const int rowBase = blockIdx.x * 32;

    if constexpr (MODE == 0) {
        // fused fc_pos: aT[r][k] = bp[k] + p.Wp[:,k]
        for (int r = 0; r < 32; ++r) {
            const float* pr = src0 + (size_t)(rowBase + r) * 3;
            float p0 = pr[0], p1 = pr[1], p2 = pr[2];
            for (int k = t; k < 384; k += 256)
                aT[r * 384 + k] = bp[k] + p0 * Wp[k] + p1 * Wp[384 + k] + p2 * Wp[768 + k];
        }
    } else {
        const int b = rowBase >> 13;
        const float4* nsrc = (const float4*)(src0) + (size_t)rowBase * 32;
        const float4* psrc = (const float4*)(pooled) + (size_t)rowBase * 32;
        const float4* msrc = (const float4*)(mean) + (size_t)b * 32;
#pragma unroll
        for (int i = 0; i < 4; ++i) {
            int f = t + 256 * i;  // 0..1023
            int r = f >> 5, cc = f & 31;
            *(float4*)(aT + r * 384 + cc * 4)       = nsrc[f];
            *(float4*)(aT + r * 384 + 128 + cc * 4) = psrc[f];
            *(float4*)(aT + r * 384 + 256 + cc * 4) = msrc[cc];
        }
    }
    // (first __syncthreads inside gemm_accum covers staging)

    const int c0 = (t & 31) * 4;
    const int r0 = (t >> 5) * 4;

    float4 acc[4];
    float4 bb0 = *(const float4*)(b0 + c0);
#pragma unroll
    for (int i = 0; i < 4; ++i) acc[i] = bb0;
    gemm_accum<true>(aT, 384, 384, W0, wT, t, r0, c0, acc);  // relu(A) @ W0 + b0

#pragma unroll
    for (int i = 0; i < 4; ++i) {  // store relu(hidden)
        float4 h = acc[i];
        h.x = fmaxf(h.x, 0.0f); h.y = fmaxf(h.y, 0.0f);
        h.z = fmaxf(h.z, 0.0f); h.w = fmaxf(h.w, 0.0f);
        *(float4*)(hT + (r0 + i) * 128 + c0) = h;
    }

    float4 bb1 = *(const float4*)(b1 + c0);
#pragma unroll
    for (int i = 0; i < 4; ++i) acc[i] = bb1;
    gemm_accum<false>(hT, 128, 128, W1, wT, t, r0, c0, acc);  // relu(h) @ W1 + b1
    gemm_accum<false>(aT, 384, 384, Ws, wT, t, r0, c0, acc);  // + A @ Ws

#pragma unroll
    for (int i = 0; i < 4; ++i)
        *(float4*)(out + (size_t)(rowBase + r0 + i) * 128 + c0) = acc[i];
}

// ---------- final projection c = net @ Wc + bc (K=128) ----------
__global__ __launch_bounds__(256, 2) void k_fcc(const float* __restrict__ A,
                                                const float* __restrict__ W,
                                                const float* __restrict__ bias,
                                                float* __restrict__ out) {
    __shared__ float aT[32 * 128];
    __shared__ float wT[32 * 128];
    const int t = threadIdx.x;
    const int rowBase = blockIdx.x * 32;
    const float4* A4 = (const float4*)(A) + (size_t)rowBase * 32;
    float4* aT4 = (float4*)aT;
#pragma unroll
    for (int i = 0; i < 4; ++i) aT4[t + 256 * i] = A4[t + 256 * i];

    const int c0 = (t & 31) * 4;
    const int r0 = (t >> 5) * 4;
    float4 acc[4];
    float4 bb = *(const float4*)(bias + c0);
#pragma unroll
    for (int i = 0; i < 4; ++i) acc[i] = bb;
    gemm_accum<false>(aT, 128, 128, W, wT, t, r0, c0, acc);
#pragma unroll
    for (int i = 0; i < 4; ++i)
        *(float4*)(out + (size_t)(rowBase + r0 + i) * 128 + c0) = acc[i];
}

// ---------- scatter-sum c into (B,128,R2) layout + counts ----------
__global__ void k_scatter_sum(const float* __restrict__ c, const int* __restrict__ idx,
                              float* __restrict__ sums, float* __restrict__ cnt) {
    int tid = blockIdx.x * 256 + threadIdx.x;
    int r = tid >> 5, ch0 = (tid & 31) << 2;
    int cellg = idx[r];
    int b = cellg >> 12, cl = cellg & 4095;
    float4 v = *(const float4*)(c + (size_t)r * 128 + ch0);
    float* base = sums + ((size_t)((b << 7) + ch0) << 12) + cl;
    atomicAdd(base,            v.x);
    atomicAdd(base + 4096,     v.y);
    atomicAdd(base + 2 * 4096, v.z);
    atomicAdd(base + 3 * 4096, v.w);
    if ((tid & 31) == 0) atomicAdd(cnt + cellg, 1.0f);
}

// ---------- out[pl][b][ch][cell] = sums/max(cnt,1), layouts already match ----------
__global__ void k_finalize(const float* __restrict__ sums, const float* __restrict__ cnt,
                           float* __restrict__ out, int pl) {
    int tid = blockIdx.x * 256 + threadIdx.x;  // 16*128*4096 = 8388608
    int cell = tid & 4095;
    int b = tid >> 19;  // / (128*4096)
    float cn = cnt[(b << 12) + cell];
    out[(size_t)pl * 8388608 + tid] = sums[tid] / fmaxf(cn, 1.0f);
}

// ---------- launch ----------
extern "C" void kernel_launch(void* const* d_in, const int* in_sizes, int n_in,
                              void* d_out, int out_size, void* d_ws, size_t ws_size,
                              hipStream_t stream) {
    const float* p  = (const float*)d_in[0];
    const float* Wp = (const float*)d_in[1];
    const float* bp = (const float*)d_in[2];
    const float* W0 = (const float*)d_in[3];
    const float* b0 = (const float*)d_in[4];
    const float* W1 = (const float*)d_in[5];
    const float* b1 = (const float*)d_in[6];
    const float* Ws = (const float*)d_in[7];
    const float* Wc = (const float*)d_in[8];
    const float* bc = (const float*)d_in[9];
    float* out = (float*)d_out;

    // workspace layout (floats): ~169.6 MB total
    float* net    = (float*)d_ws;            // 16777216
    float* pooled = net + 16777216;          // 16777216 (reused as c)
    float* seg    = pooled + 16777216;       // 8388608  (reused as sums)
    float* mean   = seg + 8388608;           // 2048
    float* cnt    = mean + 2048;             // 65536
    int*   idx    = (int*)(cnt + 65536);     // 3*131072 ints

    k_idx<<<512, 256, 0, stream>>>(p, idx);

    // block 0 (fc_pos fused)
    k_resblock<0><<<4096, 256, 0, stream>>>(p, nullptr, nullptr, Wp, bp,
                                            W0, b0, W1, b1, Ws, net);

    for (int i = 1; i < NB; ++i) {
        hipMemsetAsync(mean, 0, 2048 * 4, stream);
        k_mean<<<512, 256, 0, stream>>>(net, mean);
        for (int pl = 0; pl < 3; ++pl) {
            hipMemsetAsync(seg, 0xFF, (size_t)8388608 * 4, stream);  // -NaN sentinel
            k_scatter_max<<<16384, 256, 0, stream>>>(net, idx + pl * BT, seg);
            if (pl == 0)
                k_gather<true><<<16384, 256, 0, stream>>>(idx, seg, pooled);
            else
                k_gather<false><<<16384, 256, 0, stream>>>(idx + pl * BT, seg, pooled);
        }
        k_resblock<1><<<4096, 256, 0, stream>>>(net, pooled, mean, nullptr, nullptr,
                                                W0 + (size_t)i * 49152, b0 + i * 128,
                                                W1 + (size_t)i * 16384, b1 + i * 128,
                                                Ws + (size_t)i * 49152, net);
    }

    float* c = pooled;  // pooled no longer needed
    k_fcc<<<4096, 256, 0, stream>>>(net, Wc, bc, c);

    for (int pl = 0; pl < 3; ++pl) {
        hipMemsetAsync(seg, 0, (size_t)8388608 * 4, stream);
        hipMemsetAsync(cnt, 0, 65536 * 4, stream);
        k_scatter_sum<<<16384, 256, 0, stream>>>(c, idx + pl * BT, seg, cnt);
        k_finalize<<<32768, 256, 0, stream>>>(seg, cnt, out, pl);
    }
}

// Round 2
// 3427.109 us; speedup vs baseline: 2.9863x; 2.9863x over previous
//
#include <hip/hip_runtime.h>

#define BT (16 * 8192)
#define NB 5
#define NCELL 65536  // B * RESO^2
typedef unsigned int uint;
typedef unsigned short ushort;

// ---------- bf16 helpers (RTN-even pack, exact unpack) ----------
__device__ __forceinline__ uint f2bf(float x) {
    uint u = __float_as_uint(x);
    return (u + 0x7fffu + ((u >> 16) & 1u)) >> 16;
}
__device__ __forceinline__ float bf2f_lo(uint u) { return __uint_as_float(u << 16); }
__device__ __forceinline__ float bf2f_hi(uint u) { return __uint_as_float(u & 0xffff0000u); }

__device__ __forceinline__ void fma4(float4& acc, float a, const float4& w) {
    acc.x = fmaf(a, w.x, acc.x);
    acc.y = fmaf(a, w.y, acc.y);
    acc.z = fmaf(a, w.z, acc.z);
    acc.w = fmaf(a, w.w, acc.w);
}

// ---------- plane indices (bitwise-identical op sequence to reference) ----------
__global__ void k_idx(const float* __restrict__ p, int* __restrict__ idx) {
    int r = blockIdx.x * 256 + threadIdx.x;
    if (r >= BT) return;
    float p0 = p[3 * r + 0], p1 = p[3 * r + 1], p2 = p[3 * r + 2];
    const float DEN = (float)(1.0 + 0.1 + 1e-3);
    const float HI  = (float)(1.0 - 1e-5);
    int b = r >> 13;  // T = 8192
    float x0 = fminf(fmaxf((p0 / 8.0f) / DEN + 0.5f, 0.0f), HI);
    float x1 = fminf(fmaxf((p1 / 8.0f) / DEN + 0.5f, 0.0f), HI);
    float x2 = fminf(fmaxf((p2 / 8.0f) / DEN + 0.5f, 0.0f), HI);
    int i0 = (int)(x0 * 64.0f);
    int i1 = (int)(x1 * 64.0f);
    int i2 = (int)(x2 * 64.0f);
    int base = b << 12;
    idx[r]          = base + i0 + (i2 << 6);  // xz
    idx[BT + r]     = base + i0 + (i1 << 6);  // xy
    idx[2 * BT + r] = base + i1 + (i2 << 6);  // yz
}

// ---------- counting sort: histogram ----------
__global__ void k_hist(const int* __restrict__ idx, int* __restrict__ cnt) {
    int r = blockIdx.x * 256 + threadIdx.x;
    if (r >= BT) return;
    atomicAdd(cnt + idx[r], 1);
    atomicAdd(cnt + NCELL + idx[BT + r], 1);
    atomicAdd(cnt + 2 * NCELL + idx[2 * BT + r], 1);
}

// ---------- counting sort: per-plane exclusive scan (one block per plane) ----------
__global__ __launch_bounds__(1024) void k_scan(const int* __restrict__ cnt,
                                               int* __restrict__ starts,
                                               int* __restrict__ cursor) {
    __shared__ int sc[1024];
    int pl = blockIdx.x, t = threadIdx.x;
    const int* c = cnt + pl * NCELL;
    int base = t * 64;
    int s = 0;
    for (int i = 0; i < 64; ++i) s += c[base + i];
    sc[t] = s;
    __syncthreads();
    for (int off = 1; off < 1024; off <<= 1) {
        int v = (t >= off) ? sc[t - off] : 0;
        __syncthreads();
        sc[t] += v;
        __syncthreads();
    }
    int run = sc[t] - s;  // exclusive prefix of this chunk
    for (int i = 0; i < 64; ++i) {
        int cell = base + i;
        starts[pl * NCELL + cell] = run;
        cursor[pl * NCELL + cell] = run;
        run += c[cell];
    }
}

// ---------- counting sort: scatter point ids ----------
__global__ void k_scatter_order(const int* __restrict__ idx, int* __restrict__ cursor,
                                int* __restrict__ order) {
    int r = blockIdx.x * 256 + threadIdx.x;
    if (r >= BT) return;
    for (int pl = 0; pl < 3; ++pl) {
        int cell = idx[pl * BT + r];
        int pos = atomicAdd(cursor + pl * NCELL + cell, 1);
        order[pl * BT + pos] = r;
    }
}

// ---------- batch mean of net (B,T,128) -> (B,128) ----------
__global__ void k_mean(const float* __restrict__ net, float* __restrict__ mean) {
    __shared__ float red[256];
    int t = threadIdx.x;
    int base = blockIdx.x * 256;
    int c = t & 127, half = t >> 7;
    float s = 0.0f;
    for (int i = 0; i < 128; ++i) {
        int r = base + half + (i << 1);
        s += net[(size_t)r * 128 + c];
    }
    red[t] = s;
    __syncthreads();
    if (t < 128) {
        int b = blockIdx.x >> 5;
        atomicAdd(mean + (b << 7) + t, (red[t] + red[t + 128]) * (1.0f / 8192.0f));
    }
}

// ---------- segmented max over sorted runs: one wave per (plane,cell) ----------
__global__ __launch_bounds__(256) void k_segmax(const float* __restrict__ net,
                                                const int* __restrict__ starts,
                                                const int* __restrict__ cnt,
                                                const int* __restrict__ order,
                                                ushort* __restrict__ seg) {
    int g = blockIdx.x * 4 + (threadIdx.x >> 6);  // global cell over 3 planes
    int l = threadIdx.x & 63;
    int n = cnt[g];
    if (n == 0) return;
    int pl = g >> 16;
    const int* ord = order + pl * BT + starts[g];
    float m0 = -INFINITY, m1 = -INFINITY;
    for (int i = 0; i < n; ++i) {
        int pid = ord[i];
        float2 v = *(const float2*)(net + (size_t)pid * 128 + 2 * l);
        m0 = fmaxf(m0, v.x);
        m1 = fmaxf(m1, v.y);
    }
    ((uint*)seg)[(size_t)g * 64 + l] = f2bf(m0) | (f2bf(m1) << 16);
}

// ---------- tiled f32 GEMM accumulate: acc += (relu?)(A_lds) @ W ----------
template <bool RELU_A>
__device__ __forceinline__ void gemm_accum(const float* __restrict__ aS, int lda, int K,
                                           const float* __restrict__ Wg, float* __restrict__ wT,
                                           int t, int r0, int c0, float4 acc[4]) {
    for (int kt = 0; kt < K; kt += 32) {
        __syncthreads();
        const float4* Wg4 = (const float4*)(Wg + (size_t)kt * 128);
        float4* wT4 = (float4*)wT;
#pragma unroll
        for (int i = 0; i < 4; ++i) wT4[t + 256 * i] = Wg4[t + 256 * i];
        __syncthreads();
#pragma unroll
        for (int kk = 0; kk < 32; kk += 4) {
            float4 w[4];
#pragma unroll
            for (int j = 0; j < 4; ++j) w[j] = *(const float4*)(wT + (kk + j) * 128 + c0);
#pragma unroll
            for (int i = 0; i < 4; ++i) {
                float4 a = *(const float4*)(aS + (r0 + i) * lda + kt + kk);
                float x0 = RELU_A ? fmaxf(a.x, 0.0f) : a.x;
                float x1 = RELU_A ? fmaxf(a.y, 0.0f) : a.y;
                float x2 = RELU_A ? fmaxf(a.z, 0.0f) : a.z;
                float x3 = RELU_A ? fmaxf(a.w, 0.0f) : a.w;
                fma4(acc[i], x0, w[0]);
                fma4(acc[i], x1, w[1]);
                fma4(acc[i], x2, w[2]);
                fma4(acc[i], x3, w[3]);
            }
        }
    }
}

// ---------- fused resblock ----------
// MODE 0: A = p @ fc_pos_W + fc_pos_b; src0 = p (BT,3)
// MODE 1: A = concat(net, sum_pl seg[idx], mean_bcast); src0 = net (BT,128)
// out = A @ Ws + relu(relu(A) @ W0 + b0) @ W1 + b1
template <int MODE>
__global__ __launch_bounds__(256, 2) void k_resblock(
    const float* __restrict__ src0, const int* __restrict__ idxg,
    const ushort* __restrict__ seg, const float* __restrict__ mean,
    const float* __restrict__ Wp, const float* __restrict__ bp,
    const float* __restrict__ W0, const float* __restrict__ b0,
    const float* __restrict__ W1, const float* __restrict__ b1,
    const float* __restrict__ Ws, float* __restrict__ out) {
    __shared__ float aT[32 * 384];  // 48 KB
    __shared__ float hT[32 * 128];  // 16 KB
    __shared__ float wT[32 * 128];  // 16 KB  -> 80 KB, 2 blocks/CU
    const int t = threadIdx.x;
    const int rowBase = blockIdx.x * 32;

    if constexpr (MODE == 0) {
        for (int r = 0; r < 32; ++r) {
            const float* pr = src0 + (size_t)(rowBase + r) * 3;
            float p0 = pr[0], p1 = pr[1], p2 = pr[2];
            for (int k = t; k < 384; k += 256)
                aT[r * 384 + k] = bp[k] + p0 * Wp[k] + p1 * Wp[384 + k] + p2 * Wp[768 + k];
        }
    } else {
        const int b = rowBase >> 13;
        // net -> aT[:, 0:128]
        const float4* nsrc = (const float4*)(src0) + (size_t)rowBase * 32;
#pragma unroll
        for (int i = 0; i < 4; ++i) {
            int f = t + 256 * i;
            int r = f >> 5, cc = f & 31;
            *(float4*)(aT + r * 384 + cc * 4) = nsrc[f];
        }
        // pooled (gather+sum of 3 planes, bf16 seg) -> aT[:, 128:256]
#pragma unroll
        for (int i = 0; i < 2; ++i) {
            int f = t + 256 * i;           // 512 tasks
            int r = f >> 4, grp = f & 15;  // 8 channels per task
            int row = rowBase + r;
            float o[8] = {0, 0, 0, 0, 0, 0, 0, 0};
#pragma unroll
            for (int pl = 0; pl < 3; ++pl) {
                int cell = idxg[pl * BT + row];
                uint4 u = *(const uint4*)(seg + (size_t)pl * NCELL * 128 +
                                          (size_t)cell * 128 + grp * 8);
                o[0] += bf2f_lo(u.x); o[1] += bf2f_hi(u.x);
                o[2] += bf2f_lo(u.y); o[3] += bf2f_hi(u.y);
                o[4] += bf2f_lo(u.z); o[5] += bf2f_hi(u.z);
                o[6] += bf2f_lo(u.w); o[7] += bf2f_hi(u.w);
            }
            float4* d = (float4*)(aT + r * 384 + 128 + grp * 8);
            d[0] = make_float4(o[0], o[1], o[2], o[3]);
            d[1] = make_float4(o[4], o[5], o[6], o[7]);
        }
        // mean broadcast -> aT[:, 256:384]
        const float4* msrc = (const float4*)(mean + b * 128);
#pragma unroll
        for (int i = 0; i < 4; ++i) {
            int f = t + 256 * i;
            int r = f >> 5, cc = f & 31;
            *(float4*)(aT + r * 384 + 256 + cc * 4) = msrc[cc];
        }
    }
    // first __syncthreads inside gemm_accum covers staging

    const int c0 = (t & 31) * 4;
    const int r0 = (t >> 5) * 4;

    float4 acc[4];
    float4 bb0 = *(const float4*)(b0 + c0);
#pragma unroll
    for (int i = 0; i < 4; ++i) acc[i] = bb0;
    gemm_accum<true>(aT, 384, 384, W0, wT, t, r0, c0, acc);

#pragma unroll
    for (int i = 0; i < 4; ++i) {
        float4 h = acc[i];
        h.x = fmaxf(h.x, 0.0f); h.y = fmaxf(h.y, 0.0f);
        h.z = fmaxf(h.z, 0.0f); h.w = fmaxf(h.w, 0.0f);
        *(float4*)(hT + (r0 + i) * 128 + c0) = h;
    }

    float4 bb1 = *(const float4*)(b1 + c0);
#pragma unroll
    for (int i = 0; i < 4; ++i) acc[i] = bb1;
    gemm_accum<false>(hT, 128, 128, W1, wT, t, r0, c0, acc);
    gemm_accum<false>(aT, 384, 384, Ws, wT, t, r0, c0, acc);

#pragma unroll
    for (int i = 0; i < 4; ++i)
        *(float4*)(out + (size_t)(rowBase + r0 + i) * 128 + c0) = acc[i];
}

// ---------- final projection c = net @ Wc + bc (in-place safe per-block) ----------
__global__ __launch_bounds__(256, 2) void k_fcc(const float* __restrict__ A,
                                                const float* __restrict__ W,
                                                const float* __restrict__ bias,
                                                float* __restrict__ out) {
    __shared__ float aT[32 * 128];
    __shared__ float wT[32 * 128];
    const int t = threadIdx.x;
    const int rowBase = blockIdx.x * 32;
    const float4* A4 = (const float4*)(A) + (size_t)rowBase * 32;
    float4* aT4 = (float4*)aT;
#pragma unroll
    for (int i = 0; i < 4; ++i) aT4[t + 256 * i] = A4[t + 256 * i];

    const int c0 = (t & 31) * 4;
    const int r0 = (t >> 5) * 4;
    float4 acc[4];
    float4 bb = *(const float4*)(bias + c0);
#pragma unroll
    for (int i = 0; i < 4; ++i) acc[i] = bb;
    gemm_accum<false>(aT, 128, 128, W, wT, t, r0, c0, acc);
#pragma unroll
    for (int i = 0; i < 4; ++i)
        *(float4*)(out + (size_t)(rowBase + r0 + i) * 128 + c0) = acc[i];
}

// ---------- segmented sum over sorted runs: one wave per cell ----------
__global__ __launch_bounds__(256) void k_segsum(const float* __restrict__ c,
                                                const int* __restrict__ starts,
                                                const int* __restrict__ cnt,
                                                const int* __restrict__ order,
                                                float* __restrict__ sums, int pl) {
    int cell = blockIdx.x * 4 + (threadIdx.x >> 6);
    int l = threadIdx.x & 63;
    int n = cnt[pl * NCELL + cell];
    if (n == 0) return;
    const int* ord = order + pl * BT + starts[pl * NCELL + cell];
    float s0 = 0.f, s1 = 0.f;
    for (int i = 0; i < n; ++i) {
        int pid = ord[i];
        float2 v = *(const float2*)(c + (size_t)pid * 128 + 2 * l);
        s0 += v.x; s1 += v.y;
    }
    *(float2*)(sums + (size_t)cell * 128 + 2 * l) = make_float2(s0, s1);
}

// ---------- transpose + divide: sums(bcell,ch) -> out(pl,b,ch,cell) ----------
__global__ __launch_bounds__(256) void k_fin(const float* __restrict__ sums,
                                             const int* __restrict__ cnt,
                                             float* __restrict__ out, int pl) {
    __shared__ float tile[32][33];
    int t = threadIdx.x;
    int tx = t & 31, ty = t >> 5;
    int cl0 = (blockIdx.x & 127) << 5;
    int ch0 = (blockIdx.x >> 7) << 5;
    int b = blockIdx.y;
    int bc = b << 12;
#pragma unroll
    for (int j = 0; j < 4; ++j)
        tile[ty + 8 * j][tx] = sums[(size_t)(bc + cl0 + ty + 8 * j) * 128 + ch0 + tx];
    __syncthreads();
#pragma unroll
    for (int j = 0; j < 4; ++j) {
        int ch = ch0 + ty + 8 * j;
        int cl = cl0 + tx;
        int cn = cnt[pl * NCELL + bc + cl];
        float v = cn > 0 ? tile[tx][ty + 8 * j] / (float)cn : 0.0f;
        out[((size_t)((pl * 16 + b) * 128 + ch) << 12) + cl] = v;
    }
}

// ---------- launch ----------
extern "C" void kernel_launch(void* const* d_in, const int* in_sizes, int n_in,
                              void* d_out, int out_size, void* d_ws, size_t ws_size,
                              hipStream_t stream) {
    const float* p  = (const float*)d_in[0];
    const float* Wp = (const float*)d_in[1];
    const float* bp = (const float*)d_in[2];
    const float* W0 = (const float*)d_in[3];
    const float* b0 = (const float*)d_in[4];
    const float* W1 = (const float*)d_in[5];
    const float* b1 = (const float*)d_in[6];
    const float* Ws = (const float*)d_in[7];
    const float* Wc = (const float*)d_in[8];
    const float* bc = (const float*)d_in[9];
    float* out = (float*)d_out;

    // workspace (floats): ~123 MB
    float*  net    = (float*)d_ws;                       // 16,777,216
    ushort* seg    = (ushort*)(net + 16777216);          // 25,165,824 ushorts (12,582,912 fl)
    float*  sums   = (float*)seg;                        // alias (after pooling done)
    int*    idx    = (int*)(net + 16777216 + 12582912);  // 393,216
    int*    order  = idx + 393216;                       // 393,216
    int*    cnt    = order + 393216;                     // 196,608
    int*    starts = cnt + 196608;                       // 196,608
    int*    cursor = starts + 196608;                    // 196,608
    float*  mean   = (float*)(cursor + 196608);          // 2,048

    // --- sort points by cell, once (idx is loop-invariant) ---
    k_idx<<<512, 256, 0, stream>>>(p, idx);
    hipMemsetAsync(cnt, 0, 3 * NCELL * 4, stream);
    k_hist<<<512, 256, 0, stream>>>(idx, cnt);
    k_scan<<<3, 1024, 0, stream>>>(cnt, starts, cursor);
    k_scatter_order<<<512, 256, 0, stream>>>(idx, cursor, order);

    // --- block 0 (fc_pos fused) ---
    k_resblock<0><<<4096, 256, 0, stream>>>(p, nullptr, nullptr, nullptr, Wp, bp,
                                            W0, b0, W1, b1, Ws, net);

    for (int i = 1; i < NB; ++i) {
        hipMemsetAsync(mean, 0, 2048 * 4, stream);
        k_mean<<<512, 256, 0, stream>>>(net, mean);
        k_segmax<<<49152, 256, 0, stream>>>(net, starts, cnt, order, seg);
        k_resblock<1><<<4096, 256, 0, stream>>>(net, idx, seg, mean, nullptr, nullptr,
                                                W0 + (size_t)i * 49152, b0 + i * 128,
                                                W1 + (size_t)i * 16384, b1 + i * 128,
                                                Ws + (size_t)i * 49152, net);
    }

    // --- c = net @ Wc + bc (in-place) ---
    k_fcc<<<4096, 256, 0, stream>>>(net, Wc, bc, net);

    // --- per-plane segmented sum + transposed finalize ---
    for (int pl = 0; pl < 3; ++pl) {
        k_segsum<<<16384, 256, 0, stream>>>(net, starts, cnt, order, sums, pl);
        k_fin<<<dim3(512, 16), 256, 0, stream>>>(sums, cnt, out, pl);
    }
}

// Round 3
// 980.973 us; speedup vs baseline: 10.4328x; 3.4936x over previous
//
#include <hip/hip_runtime.h>

#define BT (16 * 8192)
#define NB 5
#define NCELL 65536  // B * RESO^2
typedef unsigned int uint;
typedef unsigned short ushort;
typedef __attribute__((ext_vector_type(8))) short bf16x8;
typedef __attribute__((ext_vector_type(4))) float f32x4;

// ---------- bf16 helpers (RTN-even pack, exact unpack) ----------
__device__ __forceinline__ uint f2bf(float x) {
    uint u = __float_as_uint(x);
    return (u + 0x7fffu + ((u >> 16) & 1u)) >> 16;
}
__device__ __forceinline__ float bf2f_lo(uint u) { return __uint_as_float(u << 16); }
__device__ __forceinline__ float bf2f_hi(uint u) { return __uint_as_float(u & 0xffff0000u); }
__device__ __forceinline__ uint pack2(float a, float b) { return f2bf(a) | (f2bf(b) << 16); }

// relu on 2 packed bf16 (sign-select to zero); rounding commutes with max(0,.)
__device__ __forceinline__ uint relu2(uint u) {
    uint m = (u >> 15) & 0x00010001u;
    return u & ~(m * 0xffffu);
}
__device__ __forceinline__ bf16x8 relu8(bf16x8 a) {
    uint4 u = *(uint4*)&a;
    u.x = relu2(u.x); u.y = relu2(u.y); u.z = relu2(u.z); u.w = relu2(u.w);
    return *(bf16x8*)&u;
}
__device__ __forceinline__ f32x4 bcast4(float x) { return (f32x4){x, x, x, x}; }

// ---------- plane indices (bitwise-identical op sequence to reference) ----------
__global__ void k_idx(const float* __restrict__ p, int* __restrict__ idx) {
    int r = blockIdx.x * 256 + threadIdx.x;
    if (r >= BT) return;
    float p0 = p[3 * r + 0], p1 = p[3 * r + 1], p2 = p[3 * r + 2];
    const float DEN = (float)(1.0 + 0.1 + 1e-3);
    const float HI  = (float)(1.0 - 1e-5);
    int b = r >> 13;  // T = 8192
    float x0 = fminf(fmaxf((p0 / 8.0f) / DEN + 0.5f, 0.0f), HI);
    float x1 = fminf(fmaxf((p1 / 8.0f) / DEN + 0.5f, 0.0f), HI);
    float x2 = fminf(fmaxf((p2 / 8.0f) / DEN + 0.5f, 0.0f), HI);
    int i0 = (int)(x0 * 64.0f);
    int i1 = (int)(x1 * 64.0f);
    int i2 = (int)(x2 * 64.0f);
    int base = b << 12;
    idx[r]          = base + i0 + (i2 << 6);  // xz
    idx[BT + r]     = base + i0 + (i1 << 6);  // xy
    idx[2 * BT + r] = base + i1 + (i2 << 6);  // yz
}

// ---------- counting sort ----------
__global__ void k_hist(const int* __restrict__ idx, int* __restrict__ cnt) {
    int r = blockIdx.x * 256 + threadIdx.x;
    if (r >= BT) return;
    atomicAdd(cnt + idx[r], 1);
    atomicAdd(cnt + NCELL + idx[BT + r], 1);
    atomicAdd(cnt + 2 * NCELL + idx[2 * BT + r], 1);
}

__global__ __launch_bounds__(1024) void k_scan(const int* __restrict__ cnt,
                                               int* __restrict__ starts,
                                               int* __restrict__ cursor) {
    __shared__ int sc[1024];
    int pl = blockIdx.x, t = threadIdx.x;
    const int* c = cnt + pl * NCELL;
    int base = t * 64;
    int s = 0;
    for (int i = 0; i < 64; ++i) s += c[base + i];
    sc[t] = s;
    __syncthreads();
    for (int off = 1; off < 1024; off <<= 1) {
        int v = (t >= off) ? sc[t - off] : 0;
        __syncthreads();
        sc[t] += v;
        __syncthreads();
    }
    int run = sc[t] - s;
    for (int i = 0; i < 64; ++i) {
        int cell = base + i;
        starts[pl * NCELL + cell] = run;
        cursor[pl * NCELL + cell] = run;
        run += c[cell];
    }
}

__global__ void k_scatter_order(const int* __restrict__ idx, int* __restrict__ cursor,
                                int* __restrict__ order) {
    int r = blockIdx.x * 256 + threadIdx.x;
    if (r >= BT) return;
    for (int pl = 0; pl < 3; ++pl) {
        int cell = idx[pl * BT + r];
        int pos = atomicAdd(cursor + pl * NCELL + cell, 1);
        order[pl * BT + pos] = r;
    }
}

// ---------- weight convert f32 row-major -> bf16 fragment layout [K/32][128][32] ----------
// mats 0-4: W0 (K=384), 5-9: W1 (K=128), 10-14: Ws (K=384), 15: Wc (K=128)
__global__ void k_wconv(const float* __restrict__ W0, const float* __restrict__ W1,
                        const float* __restrict__ Ws, const float* __restrict__ Wc,
                        ushort* __restrict__ wb) {
    int mat = blockIdx.y;
    int K = (mat < 5 || (mat >= 10 && mat < 15)) ? 384 : 128;
    int e = blockIdx.x * 256 + threadIdx.x;
    if (e >= K * 128) return;
    const float* src;
    size_t doff;
    if (mat < 5)       { src = W0 + (size_t)mat * 49152;        doff = (size_t)mat * 49152; }
    else if (mat < 10) { src = W1 + (size_t)(mat - 5) * 16384;  doff = 245760 + (size_t)(mat - 5) * 16384; }
    else if (mat < 15) { src = Ws + (size_t)(mat - 10) * 49152; doff = 327680 + (size_t)(mat - 10) * 49152; }
    else               { src = Wc;                              doff = 573440; }
    int ko = e & 31, n = (e >> 5) & 127, kt = e >> 12;
    wb[doff + e] = (ushort)f2bf(src[(size_t)(kt * 32 + ko) * 128 + n]);
}

// ---------- segmented max over sorted runs (bf16 net -> bf16 seg) ----------
__global__ __launch_bounds__(256) void k_segmax(const uint* __restrict__ netu,
                                                const int* __restrict__ starts,
                                                const int* __restrict__ cnt,
                                                const int* __restrict__ order,
                                                uint* __restrict__ segu) {
    int g = blockIdx.x * 4 + (threadIdx.x >> 6);
    int l = threadIdx.x & 63;
    int n = cnt[g];
    if (n == 0) return;
    int pl = g >> 16;
    const int* ord = order + pl * BT + starts[g];
    float m0 = -INFINITY, m1 = -INFINITY;
    for (int i = 0; i < n; ++i) {
        uint u = netu[(size_t)ord[i] * 64 + l];
        m0 = fmaxf(m0, bf2f_lo(u));
        m1 = fmaxf(m1, bf2f_hi(u));
    }
    segu[(size_t)g * 64 + l] = pack2(m0, m1);
}

// ---------- MFMA GEMM micro-kernel: acc += (relu?)(A_lds[64xK]) @ W[KxN=128 frag layout] ----------
// wave covers 64 rows x 32 cols (cols at wb already offset by n0*32)
template <bool RELU>
__device__ __forceinline__ void mfma_gemm(const ushort* __restrict__ aLDS, int lda, int nk,
                                          const ushort* __restrict__ wb, int lm, int lg,
                                          f32x4 acc[4][2]) {
    for (int kt = 0; kt < nk; ++kt) {
        bf16x8 b0 = *(const bf16x8*)(wb + kt * 4096 + lm * 32 + lg * 8);
        bf16x8 b1 = *(const bf16x8*)(wb + kt * 4096 + (16 + lm) * 32 + lg * 8);
#pragma unroll
        for (int im = 0; im < 4; ++im) {
            bf16x8 a = *(const bf16x8*)(aLDS + (im * 16 + lm) * lda + kt * 32 + lg * 8);
            if (RELU) a = relu8(a);
            acc[im][0] = __builtin_amdgcn_mfma_f32_16x16x32_bf16(a, b0, acc[im][0], 0, 0, 0);
            acc[im][1] = __builtin_amdgcn_mfma_f32_16x16x32_bf16(a, b1, acc[im][1], 0, 0, 0);
        }
    }
}

// ---------- fused resblock (bf16 MFMA) ----------
// MODE 0: A = p @ fc_pos_W + fc_pos_b; MODE 1: A = concat(net, pooled, mean)
// out(bf16) = A @ Ws + relu(relu(A) @ W0 + b0) @ W1 + b1 ; epilogue: per-batch mean atomics
template <int MODE>
__global__ __launch_bounds__(256, 2) void k_resblock(
    const float* __restrict__ p, const uint* __restrict__ netu,
    const int* __restrict__ idxg, const ushort* __restrict__ seg,
    const float* __restrict__ meanR, const float* __restrict__ Wp,
    const float* __restrict__ bp, const ushort* __restrict__ wb0,
    const float* __restrict__ b0, const ushort* __restrict__ wb1,
    const float* __restrict__ b1, const ushort* __restrict__ wbs,
    ushort* __restrict__ out, float* __restrict__ meanW) {
    __shared__ __align__(16) ushort aT[64 * 392];  // 50176 B (K=384 + pad 8)
    __shared__ __align__(16) ushort hT[64 * 136];  // 17408 B (K=128 + pad 8)
    const int t = threadIdx.x;
    const int rowBase = blockIdx.x * 64;
    const int bb = rowBase >> 13;

    if constexpr (MODE == 0) {
        for (int e = t; e < 64 * 192; e += 256) {
            int row = e / 192, q = e - row * 192;
            const float* pr = p + (size_t)(rowBase + row) * 3;
            float p0 = pr[0], p1 = pr[1], p2 = pr[2];
            int k = 2 * q;
            float v0 = bp[k]     + p0 * Wp[k]     + p1 * Wp[384 + k]     + p2 * Wp[768 + k];
            float v1 = bp[k + 1] + p0 * Wp[k + 1] + p1 * Wp[384 + k + 1] + p2 * Wp[768 + k + 1];
            ((uint*)aT)[row * 196 + q] = pack2(v0, v1);
        }
    } else {
        const uint4* nsrc = (const uint4*)netu;
#pragma unroll
        for (int i = 0; i < 4; ++i) {  // net -> aT[:,0:128]
            int u = t + 256 * i;
            int row = u >> 4, cu = u & 15;
            *(uint4*)(aT + row * 392 + cu * 8) = nsrc[(size_t)(rowBase + row) * 16 + cu];
        }
#pragma unroll
        for (int i = 0; i < 4; ++i) {  // pooled -> aT[:,128:256]
            int u = t + 256 * i;
            int row = u >> 4, grp = u & 15;
            int prow = rowBase + row;
            float o[8] = {};
#pragma unroll
            for (int pl = 0; pl < 3; ++pl) {
                int cell = idxg[pl * BT + prow];
                uint4 s4 = *(const uint4*)(seg + (size_t)(pl * NCELL + cell) * 128 + grp * 8);
                o[0] += bf2f_lo(s4.x); o[1] += bf2f_hi(s4.x);
                o[2] += bf2f_lo(s4.y); o[3] += bf2f_hi(s4.y);
                o[4] += bf2f_lo(s4.z); o[5] += bf2f_hi(s4.z);
                o[6] += bf2f_lo(s4.w); o[7] += bf2f_hi(s4.w);
            }
            uint4 d;
            d.x = pack2(o[0], o[1]); d.y = pack2(o[2], o[3]);
            d.z = pack2(o[4], o[5]); d.w = pack2(o[6], o[7]);
            *(uint4*)(aT + row * 392 + 128 + grp * 8) = d;
        }
        {  // mean broadcast -> aT[:,256:384]
            int g = t & 15, rr = t >> 4;
            const float* ms = meanR + bb * 128 + g * 8;
            uint4 d;
            d.x = pack2(ms[0], ms[1]); d.y = pack2(ms[2], ms[3]);
            d.z = pack2(ms[4], ms[5]); d.w = pack2(ms[6], ms[7]);
#pragma unroll
            for (int ii = 0; ii < 4; ++ii)
                *(uint4*)(aT + (rr + 16 * ii) * 392 + 256 + g * 8) = d;
        }
    }
    __syncthreads();

    const int l = t & 63, wid = t >> 6;
    const int n0 = wid * 32;
    const int lm = l & 15, lg = l >> 4;

    f32x4 acc[4][2];
    {
        float bi0 = b0[n0 + lm], bi1 = b0[n0 + 16 + lm];
#pragma unroll
        for (int im = 0; im < 4; ++im) { acc[im][0] = bcast4(bi0); acc[im][1] = bcast4(bi1); }
    }
    mfma_gemm<true>(aT, 392, 12, wb0 + n0 * 32, lm, lg, acc);

#pragma unroll
    for (int im = 0; im < 4; ++im)
#pragma unroll
        for (int ic = 0; ic < 2; ++ic)
#pragma unroll
            for (int j = 0; j < 4; ++j) {
                int row = im * 16 + lg * 4 + j;
                int col = n0 + ic * 16 + lm;
                hT[row * 136 + col] = (ushort)f2bf(fmaxf(acc[im][ic][j], 0.0f));
            }
    __syncthreads();

    {
        float bi0 = b1[n0 + lm], bi1 = b1[n0 + 16 + lm];
#pragma unroll
        for (int im = 0; im < 4; ++im) { acc[im][0] = bcast4(bi0); acc[im][1] = bcast4(bi1); }
    }
    mfma_gemm<false>(hT, 136, 4, wb1 + n0 * 32, lm, lg, acc);
    mfma_gemm<false>(aT, 392, 12, wbs + n0 * 32, lm, lg, acc);

#pragma unroll
    for (int im = 0; im < 4; ++im)
#pragma unroll
        for (int ic = 0; ic < 2; ++ic)
#pragma unroll
            for (int j = 0; j < 4; ++j) {
                int row = rowBase + im * 16 + lg * 4 + j;
                int col = n0 + ic * 16 + lm;
                out[(size_t)row * 128 + col] = (ushort)f2bf(acc[im][ic][j]);
            }

    // fused batch-mean contribution (next block's input)
#pragma unroll
    for (int ic = 0; ic < 2; ++ic) {
        float s = 0.0f;
#pragma unroll
        for (int im = 0; im < 4; ++im)
#pragma unroll
            for (int j = 0; j < 4; ++j) s += acc[im][ic][j];
        s += __shfl_xor(s, 16);
        s += __shfl_xor(s, 32);
        if (l < 16) atomicAdd(meanW + bb * 128 + n0 + ic * 16 + l, s * (1.0f / 8192.0f));
    }
}

// ---------- final projection c = net @ Wc + bc (bf16 in/out, in-place safe) ----------
__global__ __launch_bounds__(256, 2) void k_fcc(const uint* __restrict__ netu,
                                                const ushort* __restrict__ wbc,
                                                const float* __restrict__ bc,
                                                ushort* __restrict__ cout) {
    __shared__ __align__(16) ushort aT[64 * 136];
    const int t = threadIdx.x;
    const int rowBase = blockIdx.x * 64;
    const uint4* nsrc = (const uint4*)netu;
#pragma unroll
    for (int i = 0; i < 4; ++i) {
        int u = t + 256 * i;
        int row = u >> 4, cu = u & 15;
        *(uint4*)(aT + row * 136 + cu * 8) = nsrc[(size_t)(rowBase + row) * 16 + cu];
    }
    __syncthreads();
    const int l = t & 63, wid = t >> 6;
    const int n0 = wid * 32;
    const int lm = l & 15, lg = l >> 4;
    f32x4 acc[4][2];
    {
        float bi0 = bc[n0 + lm], bi1 = bc[n0 + 16 + lm];
#pragma unroll
        for (int im = 0; im < 4; ++im) { acc[im][0] = bcast4(bi0); acc[im][1] = bcast4(bi1); }
    }
    mfma_gemm<false>(aT, 136, 4, wbc + n0 * 32, lm, lg, acc);
#pragma unroll
    for (int im = 0; im < 4; ++im)
#pragma unroll
        for (int ic = 0; ic < 2; ++ic)
#pragma unroll
            for (int j = 0; j < 4; ++j) {
                int row = rowBase + im * 16 + lg * 4 + j;
                int col = n0 + ic * 16 + lm;
                cout[(size_t)row * 128 + col] = (ushort)f2bf(acc[im][ic][j]);
            }
}

// ---------- segmented sum over sorted runs (bf16 c -> f32 sums, cell-major) ----------
__global__ __launch_bounds__(256) void k_segsum(const uint* __restrict__ cu,
                                                const int* __restrict__ starts,
                                                const int* __restrict__ cnt,
                                                const int* __restrict__ order,
                                                float* __restrict__ sums, int pl) {
    int cell = blockIdx.x * 4 + (threadIdx.x >> 6);
    int l = threadIdx.x & 63;
    int n = cnt[pl * NCELL + cell];
    if (n == 0) return;
    const int* ord = order + pl * BT + starts[pl * NCELL + cell];
    float s0 = 0.f, s1 = 0.f;
    for (int i = 0; i < n; ++i) {
        uint u = cu[(size_t)ord[i] * 64 + l];
        s0 += bf2f_lo(u);
        s1 += bf2f_hi(u);
    }
    *(float2*)(sums + (size_t)cell * 128 + 2 * l) = make_float2(s0, s1);
}

// ---------- transpose + divide: sums(cell,ch) -> out(pl,b,ch,cell) ----------
__global__ __launch_bounds__(256) void k_fin(const float* __restrict__ sums,
                                             const int* __restrict__ cnt,
                                             float* __restrict__ out, int pl) {
    __shared__ float tile[32][33];
    int t = threadIdx.x;
    int tx = t & 31, ty = t >> 5;
    int cl0 = (blockIdx.x & 127) << 5;
    int ch0 = (blockIdx.x >> 7) << 5;
    int b = blockIdx.y;
    int bc = b << 12;
#pragma unroll
    for (int j = 0; j < 4; ++j)
        tile[ty + 8 * j][tx] = sums[(size_t)(bc + cl0 + ty + 8 * j) * 128 + ch0 + tx];
    __syncthreads();
#pragma unroll
    for (int j = 0; j < 4; ++j) {
        int ch = ch0 + ty + 8 * j;
        int cl = cl0 + tx;
        int cn = cnt[pl * NCELL + bc + cl];
        float v = cn > 0 ? tile[tx][ty + 8 * j] / (float)cn : 0.0f;
        out[((size_t)((pl * 16 + b) * 128 + ch) << 12) + cl] = v;
    }
}

// ---------- launch ----------
extern "C" void kernel_launch(void* const* d_in, const int* in_sizes, int n_in,
                              void* d_out, int out_size, void* d_ws, size_t ws_size,
                              hipStream_t stream) {
    const float* p  = (const float*)d_in[0];
    const float* Wp = (const float*)d_in[1];
    const float* bp = (const float*)d_in[2];
    const float* W0 = (const float*)d_in[3];
    const float* b0 = (const float*)d_in[4];
    const float* W1 = (const float*)d_in[5];
    const float* b1 = (const float*)d_in[6];
    const float* Ws = (const float*)d_in[7];
    const float* Wc = (const float*)d_in[8];
    const float* bc = (const float*)d_in[9];
    float* out = (float*)d_out;

    // workspace (~90 MB)
    ushort* net    = (ushort*)d_ws;             // 16,777,216 ushorts (32 MB) — also holds c
    ushort* seg    = net + 16777216;            // 25,165,824 ushorts (48 MB)
    float*  sums   = (float*)seg;               // alias (32 MB, after pooling done)
    ushort* wb     = seg + 25165824;            // 589,824 ushorts (1.18 MB)
    int*    idx    = (int*)(wb + 589824);       // 393,216 ints
    int*    order  = idx + 393216;              // 393,216
    int*    cnt    = order + 393216;            // 196,608
    int*    starts = cnt + 196608;              // 196,608
    int*    cursor = starts + 196608;           // 196,608
    float*  meanB  = (float*)(cursor + 196608); // 2 x 2048 f32 (ping-pong)

    // --- sort points by cell (idx is loop-invariant) + weight convert ---
    k_idx<<<512, 256, 0, stream>>>(p, idx);
    hipMemsetAsync(cnt, 0, 3 * NCELL * 4, stream);
    k_hist<<<512, 256, 0, stream>>>(idx, cnt);
    k_scan<<<3, 1024, 0, stream>>>(cnt, starts, cursor);
    k_scatter_order<<<512, 256, 0, stream>>>(idx, cursor, order);
    k_wconv<<<dim3(192, 16), 256, 0, stream>>>(W0, W1, Ws, Wc, wb);

    // --- block 0 (fc_pos fused), writes mean[0] ---
    hipMemsetAsync(meanB, 0, 2048 * 4, stream);
    k_resblock<0><<<2048, 256, 0, stream>>>(p, nullptr, nullptr, nullptr, nullptr, Wp, bp,
                                            wb, b0, wb + 245760, b1, wb + 327680,
                                            net, meanB);

    for (int i = 1; i < NB; ++i) {
        k_segmax<<<49152, 256, 0, stream>>>((const uint*)net, starts, cnt, order, (uint*)seg);
        hipMemsetAsync(meanB + (i & 1) * 2048, 0, 2048 * 4, stream);
        k_resblock<1><<<2048, 256, 0, stream>>>(
            nullptr, (const uint*)net, idx, seg, meanB + ((i - 1) & 1) * 2048,
            nullptr, nullptr,
            wb + (size_t)i * 49152, b0 + i * 128,
            wb + 245760 + (size_t)i * 16384, b1 + i * 128,
            wb + 327680 + (size_t)i * 49152,
            net, meanB + (i & 1) * 2048);
    }

    // --- c = net @ Wc + bc (in-place, bf16) ---
    k_fcc<<<2048, 256, 0, stream>>>((const uint*)net, wb + 573440, bc, net);

    // --- per-plane segmented sum + transposed finalize ---
    for (int pl = 0; pl < 3; ++pl) {
        k_segsum<<<16384, 256, 0, stream>>>((const uint*)net, starts, cnt, order, sums, pl);
        k_fin<<<dim3(512, 16), 256, 0, stream>>>(sums, cnt, out, pl);
    }
}

// Round 5
// 887.027 us; speedup vs baseline: 11.5377x; 1.1059x over previous
//
#include <hip/hip_runtime.h>

#define BT (16 * 8192)
#define NB 5
#define NCELL 65536  // B * RESO^2
typedef unsigned int uint;
typedef unsigned short ushort;
typedef __attribute__((ext_vector_type(8))) short bf16x8;
typedef __attribute__((ext_vector_type(4))) float f32x4;

// XOR-swizzled LDS index (ushort units). us must be a multiple of 8 (16B chunk)
// for vector access; lda must be a multiple of 8.
__device__ __forceinline__ int swz(int row, int us, int lda) {
    return row * lda + (us ^ ((row & 7) << 3));
}

// ---------- bf16 helpers (RTN-even pack, exact unpack) ----------
__device__ __forceinline__ uint f2bf(float x) {
    uint u = __float_as_uint(x);
    return (u + 0x7fffu + ((u >> 16) & 1u)) >> 16;
}
__device__ __forceinline__ float bf2f_lo(uint u) { return __uint_as_float(u << 16); }
__device__ __forceinline__ float bf2f_hi(uint u) { return __uint_as_float(u & 0xffff0000u); }
__device__ __forceinline__ uint pack2(float a, float b) { return f2bf(a) | (f2bf(b) << 16); }

// relu on 2 packed bf16; rounding commutes with max(0,.)
__device__ __forceinline__ uint relu2(uint u) {
    uint m = (u >> 15) & 0x00010001u;
    return u & ~(m * 0xffffu);
}
__device__ __forceinline__ bf16x8 relu8(bf16x8 a) {
    uint4 u = *(uint4*)&a;
    u.x = relu2(u.x); u.y = relu2(u.y); u.z = relu2(u.z); u.w = relu2(u.w);
    return *(bf16x8*)&u;
}
__device__ __forceinline__ f32x4 bcast4(float x) { return (f32x4){x, x, x, x}; }
__device__ __forceinline__ f32x4 mfma16(bf16x8 a, bf16x8 b, f32x4 c) {
    return __builtin_amdgcn_mfma_f32_16x16x32_bf16(a, b, c, 0, 0, 0);
}

// ---------- plane indices (bitwise-identical op sequence to reference) ----------
__global__ void k_idx(const float* __restrict__ p, int* __restrict__ idx) {
    int r = blockIdx.x * 256 + threadIdx.x;
    if (r >= BT) return;
    float p0 = p[3 * r + 0], p1 = p[3 * r + 1], p2 = p[3 * r + 2];
    const float DEN = (float)(1.0 + 0.1 + 1e-3);
    const float HI  = (float)(1.0 - 1e-5);
    int b = r >> 13;  // T = 8192
    float x0 = fminf(fmaxf((p0 / 8.0f) / DEN + 0.5f, 0.0f), HI);
    float x1 = fminf(fmaxf((p1 / 8.0f) / DEN + 0.5f, 0.0f), HI);
    float x2 = fminf(fmaxf((p2 / 8.0f) / DEN + 0.5f, 0.0f), HI);
    int i0 = (int)(x0 * 64.0f);
    int i1 = (int)(x1 * 64.0f);
    int i2 = (int)(x2 * 64.0f);
    int base = b << 12;
    idx[r]          = base + i0 + (i2 << 6);  // xz
    idx[BT + r]     = base + i0 + (i1 << 6);  // xy
    idx[2 * BT + r] = base + i1 + (i2 << 6);  // yz
}

// ---------- counting sort ----------
__global__ void k_hist(const int* __restrict__ idx, int* __restrict__ cnt) {
    int r = blockIdx.x * 256 + threadIdx.x;
    if (r >= BT) return;
    atomicAdd(cnt + idx[r], 1);
    atomicAdd(cnt + NCELL + idx[BT + r], 1);
    atomicAdd(cnt + 2 * NCELL + idx[2 * BT + r], 1);
}

__global__ __launch_bounds__(1024) void k_scan(const int* __restrict__ cnt,
                                               int* __restrict__ starts,
                                               int* __restrict__ cursor) {
    __shared__ int sc[1024];
    int pl = blockIdx.x, t = threadIdx.x;
    const int* c = cnt + pl * NCELL;
    int base = t * 64;
    int s = 0;
    for (int i = 0; i < 64; ++i) s += c[base + i];
    sc[t] = s;
    __syncthreads();
    for (int off = 1; off < 1024; off <<= 1) {
        int v = (t >= off) ? sc[t - off] : 0;
        __syncthreads();
        sc[t] += v;
        __syncthreads();
    }
    int run = sc[t] - s;
    for (int i = 0; i < 64; ++i) {
        int cell = base + i;
        starts[pl * NCELL + cell] = run;
        cursor[pl * NCELL + cell] = run;
        run += c[cell];
    }
}

__global__ void k_scatter_order(const int* __restrict__ idx, int* __restrict__ cursor,
                                int* __restrict__ order) {
    int r = blockIdx.x * 256 + threadIdx.x;
    if (r >= BT) return;
    for (int pl = 0; pl < 3; ++pl) {
        int cell = idx[pl * BT + r];
        int pos = atomicAdd(cursor + pl * NCELL + cell, 1);
        order[pl * BT + pos] = r;
    }
}

// ---------- weight convert f32 row-major -> bf16 fragment layout [K/32][128][32] ----------
// mats 0-4: W0 (K=384), 5-9: W1 (K=128), 10-14: Ws (K=384), 15: Wc (K=128)
__global__ void k_wconv(const float* __restrict__ W0, const float* __restrict__ W1,
                        const float* __restrict__ Ws, const float* __restrict__ Wc,
                        ushort* __restrict__ wb) {
    int mat = blockIdx.y;
    int K = (mat < 5 || (mat >= 10 && mat < 15)) ? 384 : 128;
    int e = blockIdx.x * 256 + threadIdx.x;
    if (e >= K * 128) return;
    const float* src;
    size_t doff;
    if (mat < 5)       { src = W0 + (size_t)mat * 49152;        doff = (size_t)mat * 49152; }
    else if (mat < 10) { src = W1 + (size_t)(mat - 5) * 16384;  doff = 245760 + (size_t)(mat - 5) * 16384; }
    else if (mat < 15) { src = Ws + (size_t)(mat - 10) * 49152; doff = 327680 + (size_t)(mat - 10) * 49152; }
    else               { src = Wc;                              doff = 573440; }
    int ko = e & 31, n = (e >> 5) & 127, kt = e >> 12;
    wb[doff + e] = (ushort)f2bf(src[(size_t)(kt * 32 + ko) * 128 + n]);
}

// ---------- segmented max over sorted runs (bf16 net -> bf16 seg), 2x unroll ----------
__global__ __launch_bounds__(256) void k_segmax(const uint* __restrict__ netu,
                                                const int* __restrict__ starts,
                                                const int* __restrict__ cnt,
                                                const int* __restrict__ order,
                                                uint* __restrict__ segu) {
    int g = blockIdx.x * 4 + (threadIdx.x >> 6);
    int l = threadIdx.x & 63;
    int n = cnt[g];
    if (n == 0) return;
    int pl = g >> 16;
    const int* ord = order + pl * BT + starts[g];
    float m0 = -INFINITY, m1 = -INFINITY;
    int i = 0;
    for (; i + 2 <= n; i += 2) {
        uint a = netu[(size_t)ord[i] * 64 + l];
        uint b = netu[(size_t)ord[i + 1] * 64 + l];
        m0 = fmaxf(m0, fmaxf(bf2f_lo(a), bf2f_lo(b)));
        m1 = fmaxf(m1, fmaxf(bf2f_hi(a), bf2f_hi(b)));
    }
    if (i < n) {
        uint a = netu[(size_t)ord[i] * 64 + l];
        m0 = fmaxf(m0, bf2f_lo(a));
        m1 = fmaxf(m1, bf2f_hi(a));
    }
    segu[(size_t)g * 64 + l] = pack2(m0, m1);
}

// ---------- fused resblock (bf16 MFMA, monolithic A-tile, swizzled LDS) ----------
// 512 threads = 8 waves; wave wid owns output cols [wid*16, wid*16+16), all 64 rows.
// MODE 0: A = p @ fc_pos_W + fc_pos_b; MODE 1: A = concat(net, pooled, mean)
// out(bf16) = A @ Ws + relu(relu(A) @ W0 + b0) @ W1 + b1 ; epilogue: batch-mean atomics
template <int MODE>
__global__ __launch_bounds__(512, 4) void k_resblock(
    const float* __restrict__ p, const uint* __restrict__ netu,
    const int* __restrict__ idxg, const ushort* __restrict__ seg,
    const float* __restrict__ meanR, const float* __restrict__ Wp,
    const float* __restrict__ bp, const ushort* __restrict__ wb0,
    const float* __restrict__ b0v, const ushort* __restrict__ wb1,
    const float* __restrict__ b1v, const ushort* __restrict__ wbs,
    ushort* __restrict__ out, float* __restrict__ meanW) {
    __shared__ __align__(16) ushort aT[64 * 392];  // 50176 B (lda 392 = 49x16B)
    __shared__ __align__(16) ushort hT[64 * 136];  // 17408 B
    const int t = threadIdx.x;  // 0..511
    const int rowBase = blockIdx.x * 64;
    const int bb = rowBase >> 13;

    if constexpr (MODE == 0) {
        // fc_pos fused: 64 rows x 48 col-octets
        for (int f = t; f < 3072; f += 512) {
            int row = f / 48, g = f - row * 48;
            const float* pr = p + (size_t)(rowBase + row) * 3;
            float p0 = pr[0], p1 = pr[1], p2 = pr[2];
            int k0 = g * 8;
            uint d[4];
#pragma unroll
            for (int w = 0; w < 4; ++w) {
                int k = k0 + 2 * w;
                float v0 = bp[k]     + p0 * Wp[k]     + p1 * Wp[384 + k]     + p2 * Wp[768 + k];
                float v1 = bp[k + 1] + p0 * Wp[k + 1] + p1 * Wp[384 + k + 1] + p2 * Wp[768 + k + 1];
                d[w] = pack2(v0, v1);
            }
            *(uint4*)(aT + swz(row, k0, 392)) = make_uint4(d[0], d[1], d[2], d[3]);
        }
    } else {
        const uint4* nsrc = (const uint4*)netu;
#pragma unroll
        for (int i = 0; i < 2; ++i) {  // net -> cols [0,128)
            int f = t + 512 * i;
            int row = f >> 4, cu = f & 15;
            *(uint4*)(aT + swz(row, cu * 8, 392)) = nsrc[(size_t)(rowBase + row) * 16 + cu];
        }
#pragma unroll
        for (int i = 0; i < 2; ++i) {  // pooled -> cols [128,256)
            int f = t + 512 * i;
            int row = f >> 4, grp = f & 15;
            int prow = rowBase + row;
            float o[8] = {};
#pragma unroll
            for (int pl = 0; pl < 3; ++pl) {
                int cell = idxg[pl * BT + prow];
                uint4 s4 = *(const uint4*)(seg + (size_t)(pl * NCELL + cell) * 128 + grp * 8);
                o[0] += bf2f_lo(s4.x); o[1] += bf2f_hi(s4.x);
                o[2] += bf2f_lo(s4.y); o[3] += bf2f_hi(s4.y);
                o[4] += bf2f_lo(s4.z); o[5] += bf2f_hi(s4.z);
                o[6] += bf2f_lo(s4.w); o[7] += bf2f_hi(s4.w);
            }
            uint4 d = make_uint4(pack2(o[0], o[1]), pack2(o[2], o[3]),
                                 pack2(o[4], o[5]), pack2(o[6], o[7]));
            *(uint4*)(aT + swz(row, 128 + grp * 8, 392)) = d;
        }
        {  // mean broadcast -> cols [256,384)
            int grp = t & 15, rr = t >> 4;  // rr in [0,32)
            const float* ms = meanR + bb * 128 + grp * 8;
            uint4 d = make_uint4(pack2(ms[0], ms[1]), pack2(ms[2], ms[3]),
                                 pack2(ms[4], ms[5]), pack2(ms[6], ms[7]));
#pragma unroll
            for (int ii = 0; ii < 2; ++ii) {
                int row = rr + 32 * ii;
                *(uint4*)(aT + swz(row, 256 + grp * 8, 392)) = d;
            }
        }
    }
    __syncthreads();

    const int l = t & 63, wid = t >> 6;  // wid 0..7
    const int n0 = wid * 16;
    const int lm = l & 15, lg = l >> 4;
    const ushort* w0 = wb0 + n0 * 32;
    const ushort* w1 = wb1 + n0 * 32;
    const ushort* ws = wbs + n0 * 32;

    f32x4 acc[4];
    {
        float bi = b0v[n0 + lm];
#pragma unroll
        for (int im = 0; im < 4; ++im) acc[im] = bcast4(bi);
    }
    // acc = b0 + relu(A) @ W0
#pragma unroll
    for (int kt = 0; kt < 12; ++kt) {
        bf16x8 b = *(const bf16x8*)(w0 + kt * 4096 + lm * 32 + lg * 8);
#pragma unroll
        for (int im = 0; im < 4; ++im) {
            bf16x8 a = *(const bf16x8*)(aT + swz(im * 16 + lm, kt * 32 + lg * 8, 392));
            acc[im] = mfma16(relu8(a), b, acc[im]);
        }
    }
    // h = relu(acc) -> hT (swizzled bf16)
#pragma unroll
    for (int im = 0; im < 4; ++im)
#pragma unroll
        for (int j = 0; j < 4; ++j) {
            int row = im * 16 + lg * 4 + j;
            int col = n0 + lm;
            hT[row * 136 + ((col & ~7) ^ ((row & 7) << 3)) + (col & 7)] =
                (ushort)f2bf(fmaxf(acc[im][j], 0.0f));
        }
    __syncthreads();

    {
        float si = b1v[n0 + lm];
#pragma unroll
        for (int im = 0; im < 4; ++im) acc[im] = bcast4(si);
    }
    // acc = b1 + h @ W1
#pragma unroll
    for (int kt = 0; kt < 4; ++kt) {
        bf16x8 b = *(const bf16x8*)(w1 + kt * 4096 + lm * 32 + lg * 8);
#pragma unroll
        for (int im = 0; im < 4; ++im) {
            bf16x8 a = *(const bf16x8*)(hT + swz(im * 16 + lm, kt * 32 + lg * 8, 136));
            acc[im] = mfma16(a, b, acc[im]);
        }
    }
    // acc += A @ Ws
#pragma unroll
    for (int kt = 0; kt < 12; ++kt) {
        bf16x8 b = *(const bf16x8*)(ws + kt * 4096 + lm * 32 + lg * 8);
#pragma unroll
        for (int im = 0; im < 4; ++im) {
            bf16x8 a = *(const bf16x8*)(aT + swz(im * 16 + lm, kt * 32 + lg * 8, 392));
            acc[im] = mfma16(a, b, acc[im]);
        }
    }

    // store out (bf16)
#pragma unroll
    for (int im = 0; im < 4; ++im)
#pragma unroll
        for (int j = 0; j < 4; ++j) {
            int row = rowBase + im * 16 + lg * 4 + j;
            out[(size_t)row * 128 + n0 + lm] = (ushort)f2bf(acc[im][j]);
        }

    // fused batch-mean (input to next block); cols disjoint across waves
    {
        float s = 0.0f;
#pragma unroll
        for (int im = 0; im < 4; ++im)
#pragma unroll
            for (int j = 0; j < 4; ++j) s += acc[im][j];
        s += __shfl_xor(s, 16);
        s += __shfl_xor(s, 32);
        if (l < 16) atomicAdd(meanW + bb * 128 + n0 + l, s * (1.0f / 8192.0f));
    }
}

// ---------- round-3 style non-swizzled GEMM helper (k_fcc only) ----------
__device__ __forceinline__ void mfma_gemm3(const ushort* __restrict__ aLDS, int lda, int nk,
                                           const ushort* __restrict__ wb, int lm, int lg,
                                           f32x4 acc[4][2]) {
    for (int kt = 0; kt < nk; ++kt) {
        bf16x8 b0 = *(const bf16x8*)(wb + kt * 4096 + lm * 32 + lg * 8);
        bf16x8 b1 = *(const bf16x8*)(wb + kt * 4096 + (16 + lm) * 32 + lg * 8);
#pragma unroll
        for (int im = 0; im < 4; ++im) {
            bf16x8 a = *(const bf16x8*)(aLDS + (im * 16 + lm) * lda + kt * 32 + lg * 8);
            acc[im][0] = mfma16(a, b0, acc[im][0]);
            acc[im][1] = mfma16(a, b1, acc[im][1]);
        }
    }
}

// ---------- final projection c = net @ Wc + bc (bf16 in/out, in-place safe) ----------
__global__ __launch_bounds__(256, 2) void k_fcc(const uint* __restrict__ netu,
                                                const ushort* __restrict__ wbc,
                                                const float* __restrict__ bc,
                                                ushort* __restrict__ cout) {
    __shared__ __align__(16) ushort aT[64 * 136];
    const int t = threadIdx.x;
    const int rowBase = blockIdx.x * 64;
    const uint4* nsrc = (const uint4*)netu;
#pragma unroll
    for (int i = 0; i < 4; ++i) {
        int u = t + 256 * i;
        int row = u >> 4, cu = u & 15;
        *(uint4*)(aT + row * 136 + cu * 8) = nsrc[(size_t)(rowBase + row) * 16 + cu];
    }
    __syncthreads();
    const int l = t & 63, wid = t >> 6;
    const int n0 = wid * 32;
    const int lm = l & 15, lg = l >> 4;
    f32x4 acc[4][2];
    {
        float ci0 = bc[n0 + lm], ci1 = bc[n0 + 16 + lm];
#pragma unroll
        for (int im = 0; im < 4; ++im) { acc[im][0] = bcast4(ci0); acc[im][1] = bcast4(ci1); }
    }
    mfma_gemm3(aT, 136, 4, wbc + n0 * 32, lm, lg, acc);
#pragma unroll
    for (int im = 0; im < 4; ++im)
#pragma unroll
        for (int ic = 0; ic < 2; ++ic)
#pragma unroll
            for (int j = 0; j < 4; ++j) {
                int row = rowBase + im * 16 + lg * 4 + j;
                int col = n0 + ic * 16 + lm;
                cout[(size_t)row * 128 + col] = (ushort)f2bf(acc[im][ic][j]);
            }
}

// ---------- segmented sum over sorted runs (bf16 c -> f32 sums), 2x unroll ----------
__global__ __launch_bounds__(256) void k_segsum(const uint* __restrict__ cp,
                                                const int* __restrict__ starts,
                                                const int* __restrict__ cnt,
                                                const int* __restrict__ order,
                                                float* __restrict__ sums, int pl) {
    int cell = blockIdx.x * 4 + (threadIdx.x >> 6);
    int l = threadIdx.x & 63;
    int n = cnt[pl * NCELL + cell];
    if (n == 0) return;
    const int* ord = order + pl * BT + starts[pl * NCELL + cell];
    float s0 = 0.f, s1 = 0.f;
    int i = 0;
    for (; i + 2 <= n; i += 2) {
        uint a = cp[(size_t)ord[i] * 64 + l];
        uint b = cp[(size_t)ord[i + 1] * 64 + l];
        s0 += bf2f_lo(a) + bf2f_lo(b);
        s1 += bf2f_hi(a) + bf2f_hi(b);
    }
    if (i < n) {
        uint a = cp[(size_t)ord[i] * 64 + l];
        s0 += bf2f_lo(a);
        s1 += bf2f_hi(a);
    }
    *(float2*)(sums + (size_t)cell * 128 + 2 * l) = make_float2(s0, s1);
}

// ---------- transpose + divide: sums(cell,ch) -> out(pl,b,ch,cell) ----------
__global__ __launch_bounds__(256) void k_fin(const float* __restrict__ sums,
                                             const int* __restrict__ cnt,
                                             float* __restrict__ out, int pl) {
    __shared__ float tile[32][33];
    int t = threadIdx.x;
    int tx = t & 31, ty = t >> 5;
    int cl0 = (blockIdx.x & 127) << 5;
    int ch0 = (blockIdx.x >> 7) << 5;
    int b = blockIdx.y;
    int bc = b << 12;
#pragma unroll
    for (int j = 0; j < 4; ++j)
        tile[ty + 8 * j][tx] = sums[(size_t)(bc + cl0 + ty + 8 * j) * 128 + ch0 + tx];
    __syncthreads();
#pragma unroll
    for (int j = 0; j < 4; ++j) {
        int ch = ch0 + ty + 8 * j;
        int cl = cl0 + tx;
        int cn = cnt[pl * NCELL + bc + cl];
        float v = cn > 0 ? tile[tx][ty + 8 * j] / (float)cn : 0.0f;
        out[((size_t)((pl * 16 + b) * 128 + ch) << 12) + cl] = v;
    }
}

// ---------- launch ----------
extern "C" void kernel_launch(void* const* d_in, const int* in_sizes, int n_in,
                              void* d_out, int out_size, void* d_ws, size_t ws_size,
                              hipStream_t stream) {
    const float* p  = (const float*)d_in[0];
    const float* Wp = (const float*)d_in[1];
    const float* bp = (const float*)d_in[2];
    const float* W0 = (const float*)d_in[3];
    const float* b0 = (const float*)d_in[4];
    const float* W1 = (const float*)d_in[5];
    const float* b1 = (const float*)d_in[6];
    const float* Ws = (const float*)d_in[7];
    const float* Wc = (const float*)d_in[8];
    const float* bc = (const float*)d_in[9];
    float* out = (float*)d_out;

    // workspace (~91 MB)
    ushort* net    = (ushort*)d_ws;              // 16,777,216 ushorts (32 MB) — holds c at end
    ushort* seg    = net + 16777216;             // 25,165,824 ushorts (48 MB)
    float*  sums   = (float*)seg;                // alias (32 MB, after pooling done)
    ushort* wb     = seg + 25165824;             // 589,824 ushorts
    int*    idx    = (int*)(wb + 589824);        // 393,216 ints
    int*    order  = idx + 393216;               // 393,216
    int*    cnt    = order + 393216;             // 196,608
    int*    starts = cnt + 196608;               // 196,608
    int*    cursor = starts + 196608;            // 196,608
    float*  meanB  = (float*)(cursor + 196608);  // 2 x 2048 f32 (ping-pong)

    // --- sort points by cell (idx is loop-invariant) + weight convert ---
    k_idx<<<512, 256, 0, stream>>>(p, idx);
    hipMemsetAsync(cnt, 0, 3 * NCELL * 4, stream);
    k_hist<<<512, 256, 0, stream>>>(idx, cnt);
    k_scan<<<3, 1024, 0, stream>>>(cnt, starts, cursor);
    k_scatter_order<<<512, 256, 0, stream>>>(idx, cursor, order);
    k_wconv<<<dim3(192, 16), 256, 0, stream>>>(W0, W1, Ws, Wc, wb);

    // --- block 0 (fc_pos fused), writes mean slot 0 ---
    hipMemsetAsync(meanB, 0, 2048 * 4, stream);
    k_resblock<0><<<2048, 512, 0, stream>>>(
        p, nullptr, nullptr, nullptr, nullptr, Wp, bp,
        wb, b0, wb + 245760, b1, wb + 327680, net, meanB);

    for (int i = 1; i < NB; ++i) {
        k_segmax<<<49152, 256, 0, stream>>>((const uint*)net, starts, cnt, order, (uint*)seg);
        hipMemsetAsync(meanB + (i & 1) * 2048, 0, 2048 * 4, stream);
        k_resblock<1><<<2048, 512, 0, stream>>>(
            nullptr, (const uint*)net, idx, seg, meanB + ((i - 1) & 1) * 2048,
            nullptr, nullptr,
            wb + (size_t)i * 49152, b0 + i * 128,
            wb + 245760 + (size_t)i * 16384, b1 + i * 128,
            wb + 327680 + (size_t)i * 49152,
            net, meanB + (i & 1) * 2048);
    }

    // --- c = net @ Wc + bc (in-place, bf16) ---
    k_fcc<<<2048, 256, 0, stream>>>((const uint*)net, wb + 573440, bc, net);

    // --- per-plane segmented sum + transposed finalize ---
    for (int pl = 0; pl < 3; ++pl) {
        k_segsum<<<16384, 256, 0, stream>>>((const uint*)net, starts, cnt, order, sums, pl);
        k_fin<<<dim3(512, 16), 256, 0, stream>>>(sums, cnt, out, pl);
    }
}

// Round 6
// 769.104 us; speedup vs baseline: 13.3067x; 1.1533x over previous
//
#include <hip/hip_runtime.h>

#define BT (16 * 8192)
#define NB 5
#define NCELL 65536  // B * RESO^2
typedef unsigned int uint;
typedef unsigned short ushort;
typedef __attribute__((ext_vector_type(8))) short bf16x8;
typedef __attribute__((ext_vector_type(4))) float f32x4;

// NOTE (round-5 lesson): aT lda = 392 ushorts = 196 dwords; 196 mod 32 = 4, so the
// pad already staggers rows by one 4-dword bank group -> the wave64 b128 MFMA read
// (4*row + 16*kt + 4*lg) mod 32 is perfectly bank-balanced. NO XOR swizzle here —
// adding one (round 5) collapsed the stagger to even groups only: 26M conflict cycles.

// ---------- bf16 helpers (RTN-even pack, exact unpack) ----------
__device__ __forceinline__ uint f2bf(float x) {
    uint u = __float_as_uint(x);
    return (u + 0x7fffu + ((u >> 16) & 1u)) >> 16;
}
__device__ __forceinline__ float bf2f_lo(uint u) { return __uint_as_float(u << 16); }
__device__ __forceinline__ float bf2f_hi(uint u) { return __uint_as_float(u & 0xffff0000u); }
__device__ __forceinline__ uint pack2(float a, float b) { return f2bf(a) | (f2bf(b) << 16); }

// relu on 2 packed bf16; rounding commutes with max(0,.)
__device__ __forceinline__ uint relu2(uint u) {
    uint m = (u >> 15) & 0x00010001u;
    return u & ~(m * 0xffffu);
}
__device__ __forceinline__ bf16x8 relu8(bf16x8 a) {
    uint4 u = *(uint4*)&a;
    u.x = relu2(u.x); u.y = relu2(u.y); u.z = relu2(u.z); u.w = relu2(u.w);
    return *(bf16x8*)&u;
}
__device__ __forceinline__ f32x4 bcast4(float x) { return (f32x4){x, x, x, x}; }
__device__ __forceinline__ f32x4 mfma16(bf16x8 a, bf16x8 b, f32x4 c) {
    return __builtin_amdgcn_mfma_f32_16x16x32_bf16(a, b, c, 0, 0, 0);
}

// ---------- plane indices (bitwise-identical op sequence to reference) ----------
__global__ void k_idx(const float* __restrict__ p, int* __restrict__ idx) {
    int r = blockIdx.x * 256 + threadIdx.x;
    if (r >= BT) return;
    float p0 = p[3 * r + 0], p1 = p[3 * r + 1], p2 = p[3 * r + 2];
    const float DEN = (float)(1.0 + 0.1 + 1e-3);
    const float HI  = (float)(1.0 - 1e-5);
    int b = r >> 13;  // T = 8192
    float x0 = fminf(fmaxf((p0 / 8.0f) / DEN + 0.5f, 0.0f), HI);
    float x1 = fminf(fmaxf((p1 / 8.0f) / DEN + 0.5f, 0.0f), HI);
    float x2 = fminf(fmaxf((p2 / 8.0f) / DEN + 0.5f, 0.0f), HI);
    int i0 = (int)(x0 * 64.0f);
    int i1 = (int)(x1 * 64.0f);
    int i2 = (int)(x2 * 64.0f);
    int base = b << 12;
    idx[r]          = base + i0 + (i2 << 6);  // xz
    idx[BT + r]     = base + i0 + (i1 << 6);  // xy
    idx[2 * BT + r] = base + i1 + (i2 << 6);  // yz
}

// ---------- counting sort ----------
__global__ void k_hist(const int* __restrict__ idx, int* __restrict__ cnt) {
    int r = blockIdx.x * 256 + threadIdx.x;
    if (r >= BT) return;
    atomicAdd(cnt + idx[r], 1);
    atomicAdd(cnt + NCELL + idx[BT + r], 1);
    atomicAdd(cnt + 2 * NCELL + idx[2 * BT + r], 1);
}

__global__ __launch_bounds__(1024) void k_scan(const int* __restrict__ cnt,
                                               int* __restrict__ starts,
                                               int* __restrict__ cursor) {
    __shared__ int sc[1024];
    int pl = blockIdx.x, t = threadIdx.x;
    const int* c = cnt + pl * NCELL;
    int base = t * 64;
    int s = 0;
    for (int i = 0; i < 64; ++i) s += c[base + i];
    sc[t] = s;
    __syncthreads();
    for (int off = 1; off < 1024; off <<= 1) {
        int v = (t >= off) ? sc[t - off] : 0;
        __syncthreads();
        sc[t] += v;
        __syncthreads();
    }
    int run = sc[t] - s;
    for (int i = 0; i < 64; ++i) {
        int cell = base + i;
        starts[pl * NCELL + cell] = run;
        cursor[pl * NCELL + cell] = run;
        run += c[cell];
    }
}

__global__ void k_scatter_order(const int* __restrict__ idx, int* __restrict__ cursor,
                                int* __restrict__ order) {
    int r = blockIdx.x * 256 + threadIdx.x;
    if (r >= BT) return;
    for (int pl = 0; pl < 3; ++pl) {
        int cell = idx[pl * BT + r];
        int pos = atomicAdd(cursor + pl * NCELL + cell, 1);
        order[pl * BT + pos] = r;
    }
}

// ---------- weight convert f32 row-major -> bf16 fragment layout [K/32][128][32] ----------
// mats 0-4: W0 (K=384), 5-9: W1 (K=128), 10-14: Ws (K=384), 15: Wc (K=128)
__global__ void k_wconv(const float* __restrict__ W0, const float* __restrict__ W1,
                        const float* __restrict__ Ws, const float* __restrict__ Wc,
                        ushort* __restrict__ wb) {
    int mat = blockIdx.y;
    int K = (mat < 5 || (mat >= 10 && mat < 15)) ? 384 : 128;
    int e = blockIdx.x * 256 + threadIdx.x;
    if (e >= K * 128) return;
    const float* src;
    size_t doff;
    if (mat < 5)       { src = W0 + (size_t)mat * 49152;        doff = (size_t)mat * 49152; }
    else if (mat < 10) { src = W1 + (size_t)(mat - 5) * 16384;  doff = 245760 + (size_t)(mat - 5) * 16384; }
    else if (mat < 15) { src = Ws + (size_t)(mat - 10) * 49152; doff = 327680 + (size_t)(mat - 10) * 49152; }
    else               { src = Wc;                              doff = 573440; }
    int ko = e & 31, n = (e >> 5) & 127, kt = e >> 12;
    wb[doff + e] = (ushort)f2bf(src[(size_t)(kt * 32 + ko) * 128 + n]);
}

// ---------- segmented max over sorted runs (bf16 net -> bf16 seg), 4x unroll ----------
__global__ __launch_bounds__(256) void k_segmax(const uint* __restrict__ netu,
                                                const int* __restrict__ starts,
                                                const int* __restrict__ cnt,
                                                const int* __restrict__ order,
                                                uint* __restrict__ segu) {
    int g = blockIdx.x * 4 + (threadIdx.x >> 6);
    int l = threadIdx.x & 63;
    int n = cnt[g];
    if (n == 0) return;
    int pl = g >> 16;
    const int* ord = order + pl * BT + starts[g];
    float m0 = -INFINITY, m1 = -INFINITY;
    int i = 0;
    for (; i + 4 <= n; i += 4) {
        uint a = netu[(size_t)ord[i] * 64 + l];
        uint b = netu[(size_t)ord[i + 1] * 64 + l];
        uint c = netu[(size_t)ord[i + 2] * 64 + l];
        uint d = netu[(size_t)ord[i + 3] * 64 + l];
        m0 = fmaxf(fmaxf(m0, fmaxf(bf2f_lo(a), bf2f_lo(b))), fmaxf(bf2f_lo(c), bf2f_lo(d)));
        m1 = fmaxf(fmaxf(m1, fmaxf(bf2f_hi(a), bf2f_hi(b))), fmaxf(bf2f_hi(c), bf2f_hi(d)));
    }
    for (; i < n; ++i) {
        uint a = netu[(size_t)ord[i] * 64 + l];
        m0 = fmaxf(m0, bf2f_lo(a));
        m1 = fmaxf(m1, bf2f_hi(a));
    }
    segu[(size_t)g * 64 + l] = pack2(m0, m1);
}

// ---------- fused resblock (bf16 MFMA, monolithic A-tile, padded LDS, dual-acc) ----------
// 512 threads = 8 waves; wave wid owns output cols [wid*16, wid*16+16), all 64 rows.
// MODE 0: A = p @ fc_pos_W + fc_pos_b; MODE 1: A = concat(net, pooled, mean)
// out(bf16) = A @ Ws + relu(relu(A) @ W0 + b0) @ W1 + b1 ; epilogue: batch-mean atomics
template <int MODE>
__global__ __launch_bounds__(512, 4) void k_resblock(
    const float* __restrict__ p, const uint* __restrict__ netu,
    const int* __restrict__ idxg, const ushort* __restrict__ seg,
    const float* __restrict__ meanR, const float* __restrict__ Wp,
    const float* __restrict__ bp, const ushort* __restrict__ wb0,
    const float* __restrict__ b0v, const ushort* __restrict__ wb1,
    const float* __restrict__ b1v, const ushort* __restrict__ wbs,
    ushort* __restrict__ out, float* __restrict__ meanW) {
    __shared__ __align__(16) ushort aT[64 * 392];  // 50176 B (196 dwords/row: +4-bank stagger)
    __shared__ __align__(16) ushort hT[64 * 136];  // 17408 B (68 dwords/row: +4-bank stagger)
    const int t = threadIdx.x;  // 0..511
    const int rowBase = blockIdx.x * 64;
    const int bb = rowBase >> 13;

    if constexpr (MODE == 0) {
        // fc_pos fused: 64 rows x 48 col-octets
        for (int f = t; f < 3072; f += 512) {
            int row = f / 48, g = f - row * 48;
            const float* pr = p + (size_t)(rowBase + row) * 3;
            float p0 = pr[0], p1 = pr[1], p2 = pr[2];
            int k0 = g * 8;
            uint d[4];
#pragma unroll
            for (int w = 0; w < 4; ++w) {
                int k = k0 + 2 * w;
                float v0 = bp[k]     + p0 * Wp[k]     + p1 * Wp[384 + k]     + p2 * Wp[768 + k];
                float v1 = bp[k + 1] + p0 * Wp[k + 1] + p1 * Wp[384 + k + 1] + p2 * Wp[768 + k + 1];
                d[w] = pack2(v0, v1);
            }
            *(uint4*)(aT + row * 392 + k0) = make_uint4(d[0], d[1], d[2], d[3]);
        }
    } else {
        const uint4* nsrc = (const uint4*)netu;
#pragma unroll
        for (int i = 0; i < 2; ++i) {  // net -> cols [0,128)
            int f = t + 512 * i;
            int row = f >> 4, cu = f & 15;
            *(uint4*)(aT + row * 392 + cu * 8) = nsrc[(size_t)(rowBase + row) * 16 + cu];
        }
#pragma unroll
        for (int i = 0; i < 2; ++i) {  // pooled -> cols [128,256)
            int f = t + 512 * i;
            int row = f >> 4, grp = f & 15;
            int prow = rowBase + row;
            float o[8] = {};
#pragma unroll
            for (int pl = 0; pl < 3; ++pl) {
                int cell = idxg[pl * BT + prow];
                uint4 s4 = *(const uint4*)(seg + (size_t)(pl * NCELL + cell) * 128 + grp * 8);
                o[0] += bf2f_lo(s4.x); o[1] += bf2f_hi(s4.x);
                o[2] += bf2f_lo(s4.y); o[3] += bf2f_hi(s4.y);
                o[4] += bf2f_lo(s4.z); o[5] += bf2f_hi(s4.z);
                o[6] += bf2f_lo(s4.w); o[7] += bf2f_hi(s4.w);
            }
            uint4 d = make_uint4(pack2(o[0], o[1]), pack2(o[2], o[3]),
                                 pack2(o[4], o[5]), pack2(o[6], o[7]));
            *(uint4*)(aT + row * 392 + 128 + grp * 8) = d;
        }
        {  // mean broadcast -> cols [256,384)
            int grp = t & 15, rr = t >> 4;  // rr in [0,32)
            const float* ms = meanR + bb * 128 + grp * 8;
            uint4 d = make_uint4(pack2(ms[0], ms[1]), pack2(ms[2], ms[3]),
                                 pack2(ms[4], ms[5]), pack2(ms[6], ms[7]));
#pragma unroll
            for (int ii = 0; ii < 2; ++ii) {
                int row = rr + 32 * ii;
                *(uint4*)(aT + row * 392 + 256 + grp * 8) = d;
            }
        }
    }
    __syncthreads();

    const int l = t & 63, wid = t >> 6;  // wid 0..7
    const int n0 = wid * 16;
    const int lm = l & 15, lg = l >> 4;
    const ushort* w0 = wb0 + n0 * 32;
    const ushort* w1 = wb1 + n0 * 32;
    const ushort* ws = wbs + n0 * 32;

    // dual accumulators: acc0 = b0 + relu(A)@W0 ; accS = b1 + A@Ws (single pass over aT)
    f32x4 acc0[4], accS[4];
    {
        float bi = b0v[n0 + lm];
        float si = b1v[n0 + lm];
#pragma unroll
        for (int im = 0; im < 4; ++im) { acc0[im] = bcast4(bi); accS[im] = bcast4(si); }
    }
#pragma unroll
    for (int kt = 0; kt < 12; ++kt) {
        bf16x8 b0 = *(const bf16x8*)(w0 + kt * 4096 + lm * 32 + lg * 8);
        bf16x8 bs = *(const bf16x8*)(ws + kt * 4096 + lm * 32 + lg * 8);
#pragma unroll
        for (int im = 0; im < 4; ++im) {
            bf16x8 a = *(const bf16x8*)(aT + (im * 16 + lm) * 392 + kt * 32 + lg * 8);
            acc0[im] = mfma16(relu8(a), b0, acc0[im]);
            accS[im] = mfma16(a, bs, accS[im]);
        }
    }
    // h = relu(acc0) -> hT (bf16)
#pragma unroll
    for (int im = 0; im < 4; ++im)
#pragma unroll
        for (int j = 0; j < 4; ++j) {
            int row = im * 16 + lg * 4 + j;
            hT[row * 136 + n0 + lm] = (ushort)f2bf(fmaxf(acc0[im][j], 0.0f));
        }
    __syncthreads();

    // accS += h @ W1
#pragma unroll
    for (int kt = 0; kt < 4; ++kt) {
        bf16x8 b = *(const bf16x8*)(w1 + kt * 4096 + lm * 32 + lg * 8);
#pragma unroll
        for (int im = 0; im < 4; ++im) {
            bf16x8 a = *(const bf16x8*)(hT + (im * 16 + lm) * 136 + kt * 32 + lg * 8);
            accS[im] = mfma16(a, b, accS[im]);
        }
    }

    // store out (bf16)
#pragma unroll
    for (int im = 0; im < 4; ++im)
#pragma unroll
        for (int j = 0; j < 4; ++j) {
            int row = rowBase + im * 16 + lg * 4 + j;
            out[(size_t)row * 128 + n0 + lm] = (ushort)f2bf(accS[im][j]);
        }

    // fused batch-mean (input to next block); cols disjoint across waves
    {
        float s = 0.0f;
#pragma unroll
        for (int im = 0; im < 4; ++im)
#pragma unroll
            for (int j = 0; j < 4; ++j) s += accS[im][j];
        s += __shfl_xor(s, 16);
        s += __shfl_xor(s, 32);
        if (l < 16) atomicAdd(meanW + bb * 128 + n0 + l, s * (1.0f / 8192.0f));
    }
}

// ---------- non-swizzled GEMM helper (k_fcc only) ----------
__device__ __forceinline__ void mfma_gemm3(const ushort* __restrict__ aLDS, int lda, int nk,
                                           const ushort* __restrict__ wb, int lm, int lg,
                                           f32x4 acc[4][2]) {
    for (int kt = 0; kt < nk; ++kt) {
        bf16x8 b0 = *(const bf16x8*)(wb + kt * 4096 + lm * 32 + lg * 8);
        bf16x8 b1 = *(const bf16x8*)(wb + kt * 4096 + (16 + lm) * 32 + lg * 8);
#pragma unroll
        for (int im = 0; im < 4; ++im) {
            bf16x8 a = *(const bf16x8*)(aLDS + (im * 16 + lm) * lda + kt * 32 + lg * 8);
            acc[im][0] = mfma16(a, b0, acc[im][0]);
            acc[im][1] = mfma16(a, b1, acc[im][1]);
        }
    }
}

// ---------- final projection c = net @ Wc + bc (bf16 in/out, in-place safe) ----------
__global__ __launch_bounds__(256, 2) void k_fcc(const uint* __restrict__ netu,
                                                const ushort* __restrict__ wbc,
                                                const float* __restrict__ bc,
                                                ushort* __restrict__ cout) {
    __shared__ __align__(16) ushort aT[64 * 136];
    const int t = threadIdx.x;
    const int rowBase = blockIdx.x * 64;
    const uint4* nsrc = (const uint4*)netu;
#pragma unroll
    for (int i = 0; i < 4; ++i) {
        int u = t + 256 * i;
        int row = u >> 4, cu = u & 15;
        *(uint4*)(aT + row * 136 + cu * 8) = nsrc[(size_t)(rowBase + row) * 16 + cu];
    }
    __syncthreads();
    const int l = t & 63, wid = t >> 6;
    const int n0 = wid * 32;
    const int lm = l & 15, lg = l >> 4;
    f32x4 acc[4][2];
    {
        float ci0 = bc[n0 + lm], ci1 = bc[n0 + 16 + lm];
#pragma unroll
        for (int im = 0; im < 4; ++im) { acc[im][0] = bcast4(ci0); acc[im][1] = bcast4(ci1); }
    }
    mfma_gemm3(aT, 136, 4, wbc + n0 * 32, lm, lg, acc);
#pragma unroll
    for (int im = 0; im < 4; ++im)
#pragma unroll
        for (int ic = 0; ic < 2; ++ic)
#pragma unroll
            for (int j = 0; j < 4; ++j) {
                int row = rowBase + im * 16 + lg * 4 + j;
                int col = n0 + ic * 16 + lm;
                cout[(size_t)row * 128 + col] = (ushort)f2bf(acc[im][ic][j]);
            }
}

// ---------- segmented sum over sorted runs (bf16 c -> f32 sums), 4x unroll ----------
__global__ __launch_bounds__(256) void k_segsum(const uint* __restrict__ cp,
                                                const int* __restrict__ starts,
                                                const int* __restrict__ cnt,
                                                const int* __restrict__ order,
                                                float* __restrict__ sums, int pl) {
    int cell = blockIdx.x * 4 + (threadIdx.x >> 6);
    int l = threadIdx.x & 63;
    int n = cnt[pl * NCELL + cell];
    if (n == 0) return;
    const int* ord = order + pl * BT + starts[pl * NCELL + cell];
    float s0 = 0.f, s1 = 0.f;
    int i = 0;
    for (; i + 4 <= n; i += 4) {
        uint a = cp[(size_t)ord[i] * 64 + l];
        uint b = cp[(size_t)ord[i + 1] * 64 + l];
        uint c = cp[(size_t)ord[i + 2] * 64 + l];
        uint d = cp[(size_t)ord[i + 3] * 64 + l];
        s0 += (bf2f_lo(a) + bf2f_lo(b)) + (bf2f_lo(c) + bf2f_lo(d));
        s1 += (bf2f_hi(a) + bf2f_hi(b)) + (bf2f_hi(c) + bf2f_hi(d));
    }
    for (; i < n; ++i) {
        uint a = cp[(size_t)ord[i] * 64 + l];
        s0 += bf2f_lo(a);
        s1 += bf2f_hi(a);
    }
    *(float2*)(sums + (size_t)cell * 128 + 2 * l) = make_float2(s0, s1);
}

// ---------- transpose + divide: sums(cell,ch) -> out(pl,b,ch,cell) ----------
__global__ __launch_bounds__(256) void k_fin(const float* __restrict__ sums,
                                             const int* __restrict__ cnt,
                                             float* __restrict__ out, int pl) {
    __shared__ float tile[32][33];
    int t = threadIdx.x;
    int tx = t & 31, ty = t >> 5;
    int cl0 = (blockIdx.x & 127) << 5;
    int ch0 = (blockIdx.x >> 7) << 5;
    int b = blockIdx.y;
    int bc = b << 12;
#pragma unroll
    for (int j = 0; j < 4; ++j)
        tile[ty + 8 * j][tx] = sums[(size_t)(bc + cl0 + ty + 8 * j) * 128 + ch0 + tx];
    __syncthreads();
#pragma unroll
    for (int j = 0; j < 4; ++j) {
        int ch = ch0 + ty + 8 * j;
        int cl = cl0 + tx;
        int cn = cnt[pl * NCELL + bc + cl];
        float v = cn > 0 ? tile[tx][ty + 8 * j] / (float)cn : 0.0f;
        out[((size_t)((pl * 16 + b) * 128 + ch) << 12) + cl] = v;
    }
}

// ---------- launch ----------
extern "C" void kernel_launch(void* const* d_in, const int* in_sizes, int n_in,
                              void* d_out, int out_size, void* d_ws, size_t ws_size,
                              hipStream_t stream) {
    const float* p  = (const float*)d_in[0];
    const float* Wp = (const float*)d_in[1];
    const float* bp = (const float*)d_in[2];
    const float* W0 = (const float*)d_in[3];
    const float* b0 = (const float*)d_in[4];
    const float* W1 = (const float*)d_in[5];
    const float* b1 = (const float*)d_in[6];
    const float* Ws = (const float*)d_in[7];
    const float* Wc = (const float*)d_in[8];
    const float* bc = (const float*)d_in[9];
    float* out = (float*)d_out;

    // workspace (~91 MB)
    ushort* net    = (ushort*)d_ws;              // 16,777,216 ushorts (32 MB) — holds c at end
    ushort* seg    = net + 16777216;             // 25,165,824 ushorts (48 MB)
    float*  sums   = (float*)seg;                // alias (32 MB, after pooling done)
    ushort* wb     = seg + 25165824;             // 589,824 ushorts
    int*    idx    = (int*)(wb + 589824);        // 393,216 ints
    int*    order  = idx + 393216;               // 393,216
    int*    cnt    = order + 393216;             // 196,608
    int*    starts = cnt + 196608;               // 196,608
    int*    cursor = starts + 196608;            // 196,608
    float*  meanB  = (float*)(cursor + 196608);  // 2 x 2048 f32 (ping-pong)

    // --- sort points by cell (idx is loop-invariant) + weight convert ---
    k_idx<<<512, 256, 0, stream>>>(p, idx);
    hipMemsetAsync(cnt, 0, 3 * NCELL * 4, stream);
    k_hist<<<512, 256, 0, stream>>>(idx, cnt);
    k_scan<<<3, 1024, 0, stream>>>(cnt, starts, cursor);
    k_scatter_order<<<512, 256, 0, stream>>>(idx, cursor, order);
    k_wconv<<<dim3(192, 16), 256, 0, stream>>>(W0, W1, Ws, Wc, wb);

    // --- block 0 (fc_pos fused), writes mean slot 0 ---
    hipMemsetAsync(meanB, 0, 2048 * 4, stream);
    k_resblock<0><<<2048, 512, 0, stream>>>(
        p, nullptr, nullptr, nullptr, nullptr, Wp, bp,
        wb, b0, wb + 245760, b1, wb + 327680, net, meanB);

    for (int i = 1; i < NB; ++i) {
        k_segmax<<<49152, 256, 0, stream>>>((const uint*)net, starts, cnt, order, (uint*)seg);
        hipMemsetAsync(meanB + (i & 1) * 2048, 0, 2048 * 4, stream);
        k_resblock<1><<<2048, 512, 0, stream>>>(
            nullptr, (const uint*)net, idx, seg, meanB + ((i - 1) & 1) * 2048,
            nullptr, nullptr,
            wb + (size_t)i * 49152, b0 + i * 128,
            wb + 245760 + (size_t)i * 16384, b1 + i * 128,
            wb + 327680 + (size_t)i * 49152,
            net, meanB + (i & 1) * 2048);
    }

    // --- c = net @ Wc + bc (in-place, bf16) ---
    k_fcc<<<2048, 256, 0, stream>>>((const uint*)net, wb + 573440, bc, net);

    // --- per-plane segmented sum + transposed finalize ---
    for (int pl = 0; pl < 3; ++pl) {
        k_segsum<<<16384, 256, 0, stream>>>((const uint*)net, starts, cnt, order, sums, pl);
        k_fin<<<dim3(512, 16), 256, 0, stream>>>(sums, cnt, out, pl);
    }
}

// Round 7
// 765.137 us; speedup vs baseline: 13.3757x; 1.0052x over previous
//
#include <hip/hip_runtime.h>

#define BT (16 * 8192)
#define NB 5
#define NCELL 65536  // B * RESO^2
typedef unsigned int uint;
typedef unsigned short ushort;
typedef __attribute__((ext_vector_type(8))) short bf16x8;
typedef __attribute__((ext_vector_type(4))) float f32x4;

// NOTE (round-5 lesson): aT lda in dwords must be ≡ 4 mod 32 so rows stagger by one
// 4-dword bank group -> wave64 b128 MFMA reads are bank-balanced. 392 us (196 dw) and
// 264 us (132 dw) both satisfy this. NO XOR swizzle (round 5: it collapsed the stagger).

// ---------- bf16 helpers (RTN-even pack, exact unpack) ----------
__device__ __forceinline__ uint f2bf(float x) {
    uint u = __float_as_uint(x);
    return (u + 0x7fffu + ((u >> 16) & 1u)) >> 16;
}
__device__ __forceinline__ float bf2f_lo(uint u) { return __uint_as_float(u << 16); }
__device__ __forceinline__ float bf2f_hi(uint u) { return __uint_as_float(u & 0xffff0000u); }
__device__ __forceinline__ uint pack2(float a, float b) { return f2bf(a) | (f2bf(b) << 16); }

// relu on 2 packed bf16; rounding commutes with max(0,.)
__device__ __forceinline__ uint relu2(uint u) {
    uint m = (u >> 15) & 0x00010001u;
    return u & ~(m * 0xffffu);
}
__device__ __forceinline__ bf16x8 relu8(bf16x8 a) {
    uint4 u = *(uint4*)&a;
    u.x = relu2(u.x); u.y = relu2(u.y); u.z = relu2(u.z); u.w = relu2(u.w);
    return *(bf16x8*)&u;
}
__device__ __forceinline__ f32x4 bcast4(float x) { return (f32x4){x, x, x, x}; }
__device__ __forceinline__ f32x4 mfma16(bf16x8 a, bf16x8 b, f32x4 c) {
    return __builtin_amdgcn_mfma_f32_16x16x32_bf16(a, b, c, 0, 0, 0);
}

// ---------- plane indices (bitwise-identical op sequence to reference) ----------
__global__ void k_idx(const float* __restrict__ p, int* __restrict__ idx) {
    int r = blockIdx.x * 256 + threadIdx.x;
    if (r >= BT) return;
    float p0 = p[3 * r + 0], p1 = p[3 * r + 1], p2 = p[3 * r + 2];
    const float DEN = (float)(1.0 + 0.1 + 1e-3);
    const float HI  = (float)(1.0 - 1e-5);
    int b = r >> 13;  // T = 8192
    float x0 = fminf(fmaxf((p0 / 8.0f) / DEN + 0.5f, 0.0f), HI);
    float x1 = fminf(fmaxf((p1 / 8.0f) / DEN + 0.5f, 0.0f), HI);
    float x2 = fminf(fmaxf((p2 / 8.0f) / DEN + 0.5f, 0.0f), HI);
    int i0 = (int)(x0 * 64.0f);
    int i1 = (int)(x1 * 64.0f);
    int i2 = (int)(x2 * 64.0f);
    int base = b << 12;
    idx[r]          = base + i0 + (i2 << 6);  // xz
    idx[BT + r]     = base + i0 + (i1 << 6);  // xy
    idx[2 * BT + r] = base + i1 + (i2 << 6);  // yz
}

// ---------- counting sort ----------
__global__ void k_hist(const int* __restrict__ idx, int* __restrict__ cnt) {
    int r = blockIdx.x * 256 + threadIdx.x;
    if (r >= BT) return;
    atomicAdd(cnt + idx[r], 1);
    atomicAdd(cnt + NCELL + idx[BT + r], 1);
    atomicAdd(cnt + 2 * NCELL + idx[2 * BT + r], 1);
}

__global__ __launch_bounds__(1024) void k_scan(const int* __restrict__ cnt,
                                               int* __restrict__ starts,
                                               int* __restrict__ cursor) {
    __shared__ int sc[1024];
    int pl = blockIdx.x, t = threadIdx.x;
    const int* c = cnt + pl * NCELL;
    int base = t * 64;
    int s = 0;
    for (int i = 0; i < 64; ++i) s += c[base + i];
    sc[t] = s;
    __syncthreads();
    for (int off = 1; off < 1024; off <<= 1) {
        int v = (t >= off) ? sc[t - off] : 0;
        __syncthreads();
        sc[t] += v;
        __syncthreads();
    }
    int run = sc[t] - s;
    for (int i = 0; i < 64; ++i) {
        int cell = base + i;
        starts[pl * NCELL + cell] = run;
        cursor[pl * NCELL + cell] = run;
        run += c[cell];
    }
}

__global__ void k_scatter_order(const int* __restrict__ idx, int* __restrict__ cursor,
                                int* __restrict__ order) {
    int r = blockIdx.x * 256 + threadIdx.x;
    if (r >= BT) return;
    for (int pl = 0; pl < 3; ++pl) {
        int cell = idx[pl * BT + r];
        int pos = atomicAdd(cursor + pl * NCELL + cell, 1);
        order[pl * BT + pos] = r;
    }
}

// ---------- weight convert f32 row-major -> bf16 fragment layout [K/32][128][32] ----------
// mats 0-4: W0 (K=384), 5-9: W1 (K=128), 10-14: Ws (K=384), 15: Wc (K=128)
__global__ void k_wconv(const float* __restrict__ W0, const float* __restrict__ W1,
                        const float* __restrict__ Ws, const float* __restrict__ Wc,
                        ushort* __restrict__ wb) {
    int mat = blockIdx.y;
    int K = (mat < 5 || (mat >= 10 && mat < 15)) ? 384 : 128;
    int e = blockIdx.x * 256 + threadIdx.x;
    if (e >= K * 128) return;
    const float* src;
    size_t doff;
    if (mat < 5)       { src = W0 + (size_t)mat * 49152;        doff = (size_t)mat * 49152; }
    else if (mat < 10) { src = W1 + (size_t)(mat - 5) * 16384;  doff = 245760 + (size_t)(mat - 5) * 16384; }
    else if (mat < 15) { src = Ws + (size_t)(mat - 10) * 49152; doff = 327680 + (size_t)(mat - 10) * 49152; }
    else               { src = Wc;                              doff = 573440; }
    int ko = e & 31, n = (e >> 5) & 127, kt = e >> 12;
    wb[doff + e] = (ushort)f2bf(src[(size_t)(kt * 32 + ko) * 128 + n]);
}

// ---------- per-batch mean row-vectors (rank-1 factorization of the mean third) ----------
// rv0[b][n] = b0[n] + sum_k relu(mean[b][k]) * W0[256+k][n]
// rvS[b][n] = b1[n] + sum_k mean[b][k]       * Ws[256+k][n]
__global__ __launch_bounds__(128) void k_meanvec(const float* __restrict__ meanB,
                                                 const ushort* __restrict__ wb0,
                                                 const float* __restrict__ b0v,
                                                 const ushort* __restrict__ wbs,
                                                 const float* __restrict__ b1v,
                                                 float* __restrict__ rv0,
                                                 float* __restrict__ rvS) {
    __shared__ float ms[128];
    int b = blockIdx.x, n = threadIdx.x;
    ms[n] = meanB[b * 128 + n];
    __syncthreads();
    float s0 = b0v[n], ss = b1v[n];
#pragma unroll 4
    for (int k = 0; k < 128; ++k) {
        float mv = ms[k];
        int kt = 8 + (k >> 5), ko = k & 31;
        float w0 = bf2f_lo((uint)wb0[kt * 4096 + n * 32 + ko]);
        float ws = bf2f_lo((uint)wbs[kt * 4096 + n * 32 + ko]);
        s0 = fmaf(fmaxf(mv, 0.0f), w0, s0);
        ss = fmaf(mv, ws, ss);
    }
    rv0[b * 128 + n] = s0;
    rvS[b * 128 + n] = ss;
}

// ---------- segmented max over sorted runs (bf16 net -> bf16 seg) ----------
// n is wave-uniform; tail (<4) issues all loads independently before reducing.
__global__ __launch_bounds__(256) void k_segmax(const uint* __restrict__ netu,
                                                const int* __restrict__ starts,
                                                const int* __restrict__ cnt,
                                                const int* __restrict__ order,
                                                uint* __restrict__ segu) {
    int g = blockIdx.x * 4 + (threadIdx.x >> 6);
    int l = threadIdx.x & 63;
    int n = cnt[g];
    if (n == 0) return;
    int pl = g >> 16;
    const int* ord = order + pl * BT + starts[g];
    float m0 = -INFINITY, m1 = -INFINITY;
    int i = 0;
    for (; i + 4 <= n; i += 4) {
        uint a = netu[(size_t)ord[i] * 64 + l];
        uint b = netu[(size_t)ord[i + 1] * 64 + l];
        uint c = netu[(size_t)ord[i + 2] * 64 + l];
        uint d = netu[(size_t)ord[i + 3] * 64 + l];
        m0 = fmaxf(fmaxf(m0, fmaxf(bf2f_lo(a), bf2f_lo(b))), fmaxf(bf2f_lo(c), bf2f_lo(d)));
        m1 = fmaxf(fmaxf(m1, fmaxf(bf2f_hi(a), bf2f_hi(b))), fmaxf(bf2f_hi(c), bf2f_hi(d)));
    }
    int rem = n - i;
    if (rem > 0) {
        uint a = netu[(size_t)ord[i] * 64 + l];
        uint b = (rem > 1) ? netu[(size_t)ord[i + 1] * 64 + l] : a;
        uint c = (rem > 2) ? netu[(size_t)ord[i + 2] * 64 + l] : a;
        m0 = fmaxf(m0, fmaxf(bf2f_lo(a), fmaxf(bf2f_lo(b), bf2f_lo(c))));
        m1 = fmaxf(m1, fmaxf(bf2f_hi(a), fmaxf(bf2f_hi(b), bf2f_hi(c))));
    }
    segu[(size_t)g * 64 + l] = pack2(m0, m1);
}

// ---------- fused resblock (bf16 MFMA, padded LDS, dual-acc, rank-1 mean) ----------
// 512 threads = 8 waves; wave wid owns output cols [wid*16, wid*16+16), all 64 rows.
// MODE 0: A = p @ fc_pos_W + fc_pos_b (K=384). MODE 1: A = concat(net, pooled) (K=256),
//         mean third folded into acc init via rv0/rvS.
// out(bf16) = A @ Ws + relu(relu(A) @ W0 + b0) @ W1 + b1 ; epilogue: batch-mean atomics
template <int MODE>
__global__ __launch_bounds__(512, 6) void k_resblock(
    const float* __restrict__ p, const uint* __restrict__ netu,
    const int* __restrict__ idxg, const ushort* __restrict__ seg,
    const float* __restrict__ rv0, const float* __restrict__ rvS,
    const float* __restrict__ Wp, const float* __restrict__ bp,
    const ushort* __restrict__ wb0, const float* __restrict__ b0v,
    const ushort* __restrict__ wb1, const float* __restrict__ b1v,
    const ushort* __restrict__ wbs,
    ushort* __restrict__ out, float* __restrict__ meanW) {
    constexpr int LDA = (MODE == 0) ? 392 : 264;  // dwords/row ≡ 4 mod 32 (bank stagger)
    constexpr int NKT = (MODE == 0) ? 12 : 8;
    __shared__ __align__(16) ushort aT[64 * LDA];
    __shared__ __align__(16) ushort hT[64 * 136];
    const int t = threadIdx.x;  // 0..511
    const int rowBase = blockIdx.x * 64;
    const int bb = rowBase >> 13;

    if constexpr (MODE == 0) {
        // fc_pos fused: 64 rows x 48 col-octets
        for (int f = t; f < 3072; f += 512) {
            int row = f / 48, g = f - row * 48;
            const float* pr = p + (size_t)(rowBase + row) * 3;
            float p0 = pr[0], p1 = pr[1], p2 = pr[2];
            int k0 = g * 8;
            uint d[4];
#pragma unroll
            for (int w = 0; w < 4; ++w) {
                int k = k0 + 2 * w;
                float v0 = bp[k]     + p0 * Wp[k]     + p1 * Wp[384 + k]     + p2 * Wp[768 + k];
                float v1 = bp[k + 1] + p0 * Wp[k + 1] + p1 * Wp[384 + k + 1] + p2 * Wp[768 + k + 1];
                d[w] = pack2(v0, v1);
            }
            *(uint4*)(aT + row * LDA + k0) = make_uint4(d[0], d[1], d[2], d[3]);
        }
    } else {
        const uint4* nsrc = (const uint4*)netu;
#pragma unroll
        for (int i = 0; i < 2; ++i) {  // net -> cols [0,128)
            int f = t + 512 * i;
            int row = f >> 4, cu = f & 15;
            *(uint4*)(aT + row * LDA + cu * 8) = nsrc[(size_t)(rowBase + row) * 16 + cu];
        }
#pragma unroll
        for (int i = 0; i < 2; ++i) {  // pooled -> cols [128,256)
            int f = t + 512 * i;
            int row = f >> 4, grp = f & 15;
            int prow = rowBase + row;
            float o[8] = {};
#pragma unroll
            for (int pl = 0; pl < 3; ++pl) {
                int cell = idxg[pl * BT + prow];
                uint4 s4 = *(const uint4*)(seg + (size_t)(pl * NCELL + cell) * 128 + grp * 8);
                o[0] += bf2f_lo(s4.x); o[1] += bf2f_hi(s4.x);
                o[2] += bf2f_lo(s4.y); o[3] += bf2f_hi(s4.y);
                o[4] += bf2f_lo(s4.z); o[5] += bf2f_hi(s4.z);
                o[6] += bf2f_lo(s4.w); o[7] += bf2f_hi(s4.w);
            }
            uint4 d = make_uint4(pack2(o[0], o[1]), pack2(o[2], o[3]),
                                 pack2(o[4], o[5]), pack2(o[6], o[7]));
            *(uint4*)(aT + row * LDA + 128 + grp * 8) = d;
        }
    }
    __syncthreads();

    const int l = t & 63, wid = t >> 6;  // wid 0..7
    const int n0 = wid * 16;
    const int lm = l & 15, lg = l >> 4;
    const ushort* w0 = wb0 + n0 * 32;
    const ushort* w1 = wb1 + n0 * 32;
    const ushort* ws = wbs + n0 * 32;

    // dual accumulators: acc0 = (b0[+mean]) + relu(A)@W0 ; accS = (b1[+mean]) + A@Ws
    f32x4 acc0[4], accS[4];
    {
        float bi, si;
        if constexpr (MODE == 0) { bi = b0v[n0 + lm];            si = b1v[n0 + lm]; }
        else                     { bi = rv0[bb * 128 + n0 + lm]; si = rvS[bb * 128 + n0 + lm]; }
#pragma unroll
        for (int im = 0; im < 4; ++im) { acc0[im] = bcast4(bi); accS[im] = bcast4(si); }
    }
#pragma unroll
    for (int kt = 0; kt < NKT; ++kt) {
        bf16x8 b0 = *(const bf16x8*)(w0 + kt * 4096 + lm * 32 + lg * 8);
        bf16x8 bs = *(const bf16x8*)(ws + kt * 4096 + lm * 32 + lg * 8);
#pragma unroll
        for (int im = 0; im < 4; ++im) {
            bf16x8 a = *(const bf16x8*)(aT + (im * 16 + lm) * LDA + kt * 32 + lg * 8);
            acc0[im] = mfma16(relu8(a), b0, acc0[im]);
            accS[im] = mfma16(a, bs, accS[im]);
        }
    }
    // h = relu(acc0) -> hT (bf16)
#pragma unroll
    for (int im = 0; im < 4; ++im)
#pragma unroll
        for (int j = 0; j < 4; ++j) {
            int row = im * 16 + lg * 4 + j;
            hT[row * 136 + n0 + lm] = (ushort)f2bf(fmaxf(acc0[im][j], 0.0f));
        }
    __syncthreads();

    // accS += h @ W1
#pragma unroll
    for (int kt = 0; kt < 4; ++kt) {
        bf16x8 b = *(const bf16x8*)(w1 + kt * 4096 + lm * 32 + lg * 8);
#pragma unroll
        for (int im = 0; im < 4; ++im) {
            bf16x8 a = *(const bf16x8*)(hT + (im * 16 + lm) * 136 + kt * 32 + lg * 8);
            accS[im] = mfma16(a, b, accS[im]);
        }
    }

    // store out (bf16)
#pragma unroll
    for (int im = 0; im < 4; ++im)
#pragma unroll
        for (int j = 0; j < 4; ++j) {
            int row = rowBase + im * 16 + lg * 4 + j;
            out[(size_t)row * 128 + n0 + lm] = (ushort)f2bf(accS[im][j]);
        }

    // fused batch-mean (input to next block's meanvec); cols disjoint across waves
    if (meanW) {
        float s = 0.0f;
#pragma unroll
        for (int im = 0; im < 4; ++im)
#pragma unroll
            for (int j = 0; j < 4; ++j) s += accS[im][j];
        s += __shfl_xor(s, 16);
        s += __shfl_xor(s, 32);
        if (l < 16) atomicAdd(meanW + bb * 128 + n0 + l, s * (1.0f / 8192.0f));
    }
}

// ---------- non-swizzled GEMM helper (k_fcc only) ----------
__device__ __forceinline__ void mfma_gemm3(const ushort* __restrict__ aLDS, int lda, int nk,
                                           const ushort* __restrict__ wb, int lm, int lg,
                                           f32x4 acc[4][2]) {
    for (int kt = 0; kt < nk; ++kt) {
        bf16x8 b0 = *(const bf16x8*)(wb + kt * 4096 + lm * 32 + lg * 8);
        bf16x8 b1 = *(const bf16x8*)(wb + kt * 4096 + (16 + lm) * 32 + lg * 8);
#pragma unroll
        for (int im = 0; im < 4; ++im) {
            bf16x8 a = *(const bf16x8*)(aLDS + (im * 16 + lm) * lda + kt * 32 + lg * 8);
            acc[im][0] = mfma16(a, b0, acc[im][0]);
            acc[im][1] = mfma16(a, b1, acc[im][1]);
        }
    }
}

// ---------- final projection c = net @ Wc + bc (bf16 in/out, in-place safe) ----------
__global__ __launch_bounds__(256, 2) void k_fcc(const uint* __restrict__ netu,
                                                const ushort* __restrict__ wbc,
                                                const float* __restrict__ bc,
                                                ushort* __restrict__ cout) {
    __shared__ __align__(16) ushort aT[64 * 136];
    const int t = threadIdx.x;
    const int rowBase = blockIdx.x * 64;
    const uint4* nsrc = (const uint4*)netu;
#pragma unroll
    for (int i = 0; i < 4; ++i) {
        int u = t + 256 * i;
        int row = u >> 4, cu = u & 15;
        *(uint4*)(aT + row * 136 + cu * 8) = nsrc[(size_t)(rowBase + row) * 16 + cu];
    }
    __syncthreads();
    const int l = t & 63, wid = t >> 6;
    const int n0 = wid * 32;
    const int lm = l & 15, lg = l >> 4;
    f32x4 acc[4][2];
    {
        float ci0 = bc[n0 + lm], ci1 = bc[n0 + 16 + lm];
#pragma unroll
        for (int im = 0; im < 4; ++im) { acc[im][0] = bcast4(ci0); acc[im][1] = bcast4(ci1); }
    }
    mfma_gemm3(aT, 136, 4, wbc + n0 * 32, lm, lg, acc);
#pragma unroll
    for (int im = 0; im < 4; ++im)
#pragma unroll
        for (int ic = 0; ic < 2; ++ic)
#pragma unroll
            for (int j = 0; j < 4; ++j) {
                int row = rowBase + im * 16 + lg * 4 + j;
                int col = n0 + ic * 16 + lm;
                cout[(size_t)row * 128 + col] = (ushort)f2bf(acc[im][ic][j]);
            }
}

// ---------- segmented sum over sorted runs (bf16 c -> f32 sums) ----------
__global__ __launch_bounds__(256) void k_segsum(const uint* __restrict__ cp,
                                                const int* __restrict__ starts,
                                                const int* __restrict__ cnt,
                                                const int* __restrict__ order,
                                                float* __restrict__ sums, int pl) {
    int cell = blockIdx.x * 4 + (threadIdx.x >> 6);
    int l = threadIdx.x & 63;
    int n = cnt[pl * NCELL + cell];
    if (n == 0) return;
    const int* ord = order + pl * BT + starts[pl * NCELL + cell];
    float s0 = 0.f, s1 = 0.f;
    int i = 0;
    for (; i + 4 <= n; i += 4) {
        uint a = cp[(size_t)ord[i] * 64 + l];
        uint b = cp[(size_t)ord[i + 1] * 64 + l];
        uint c = cp[(size_t)ord[i + 2] * 64 + l];
        uint d = cp[(size_t)ord[i + 3] * 64 + l];
        s0 += (bf2f_lo(a) + bf2f_lo(b)) + (bf2f_lo(c) + bf2f_lo(d));
        s1 += (bf2f_hi(a) + bf2f_hi(b)) + (bf2f_hi(c) + bf2f_hi(d));
    }
    int rem = n - i;
    if (rem > 0) {
        uint a = cp[(size_t)ord[i] * 64 + l];
        uint b = (rem > 1) ? cp[(size_t)ord[i + 1] * 64 + l] : 0u;
        uint c = (rem > 2) ? cp[(size_t)ord[i + 2] * 64 + l] : 0u;
        s0 += bf2f_lo(a) + (bf2f_lo(b) + bf2f_lo(c));
        s1 += bf2f_hi(a) + (bf2f_hi(b) + bf2f_hi(c));
    }
    *(float2*)(sums + (size_t)cell * 128 + 2 * l) = make_float2(s0, s1);
}

// ---------- transpose + divide: sums(cell,ch) -> out(pl,b,ch,cell) ----------
__global__ __launch_bounds__(256) void k_fin(const float* __restrict__ sums,
                                             const int* __restrict__ cnt,
                                             float* __restrict__ out, int pl) {
    __shared__ float tile[32][33];
    int t = threadIdx.x;
    int tx = t & 31, ty = t >> 5;
    int cl0 = (blockIdx.x & 127) << 5;
    int ch0 = (blockIdx.x >> 7) << 5;
    int b = blockIdx.y;
    int bc = b << 12;
#pragma unroll
    for (int j = 0; j < 4; ++j)
        tile[ty + 8 * j][tx] = sums[(size_t)(bc + cl0 + ty + 8 * j) * 128 + ch0 + tx];
    __syncthreads();
#pragma unroll
    for (int j = 0; j < 4; ++j) {
        int ch = ch0 + ty + 8 * j;
        int cl = cl0 + tx;
        int cn = cnt[pl * NCELL + bc + cl];
        float v = cn > 0 ? tile[tx][ty + 8 * j] / (float)cn : 0.0f;
        out[((size_t)((pl * 16 + b) * 128 + ch) << 12) + cl] = v;
    }
}

// ---------- launch ----------
extern "C" void kernel_launch(void* const* d_in, const int* in_sizes, int n_in,
                              void* d_out, int out_size, void* d_ws, size_t ws_size,
                              hipStream_t stream) {
    const float* p  = (const float*)d_in[0];
    const float* Wp = (const float*)d_in[1];
    const float* bp = (const float*)d_in[2];
    const float* W0 = (const float*)d_in[3];
    const float* b0 = (const float*)d_in[4];
    const float* W1 = (const float*)d_in[5];
    const float* b1 = (const float*)d_in[6];
    const float* Ws = (const float*)d_in[7];
    const float* Wc = (const float*)d_in[8];
    const float* bc = (const float*)d_in[9];
    float* out = (float*)d_out;

    // workspace (~91 MB)
    ushort* net    = (ushort*)d_ws;              // 16,777,216 ushorts (32 MB) — holds c at end
    ushort* seg    = net + 16777216;             // 25,165,824 ushorts (48 MB)
    float*  sums   = (float*)seg;                // alias (32 MB, after pooling done)
    ushort* wb     = seg + 25165824;             // 589,824 ushorts
    int*    idx    = (int*)(wb + 589824);        // 393,216 ints
    int*    order  = idx + 393216;               // 393,216
    int*    cnt    = order + 393216;             // 196,608
    int*    starts = cnt + 196608;               // 196,608
    int*    cursor = starts + 196608;            // 196,608
    float*  meanB  = (float*)(cursor + 196608);  // 2 x 2048 f32 (ping-pong)
    float*  rv0    = meanB + 2 * 2048;           // 2048
    float*  rvS    = rv0 + 2048;                 // 2048

    // --- sort points by cell (idx is loop-invariant) + weight convert ---
    k_idx<<<512, 256, 0, stream>>>(p, idx);
    hipMemsetAsync(cnt, 0, 3 * NCELL * 4, stream);
    k_hist<<<512, 256, 0, stream>>>(idx, cnt);
    k_scan<<<3, 1024, 0, stream>>>(cnt, starts, cursor);
    k_scatter_order<<<512, 256, 0, stream>>>(idx, cursor, order);
    k_wconv<<<dim3(192, 16), 256, 0, stream>>>(W0, W1, Ws, Wc, wb);

    // --- block 0 (fc_pos fused), writes mean slot 0 ---
    hipMemsetAsync(meanB, 0, 2048 * 4, stream);
    k_resblock<0><<<2048, 512, 0, stream>>>(
        p, nullptr, nullptr, nullptr, nullptr, nullptr, Wp, bp,
        wb, b0, wb + 245760, b1, wb + 327680, net, meanB);

    for (int i = 1; i < NB; ++i) {
        const ushort* wb0i = wb + (size_t)i * 49152;
        const ushort* wb1i = wb + 245760 + (size_t)i * 16384;
        const ushort* wbsi = wb + 327680 + (size_t)i * 49152;
        k_segmax<<<49152, 256, 0, stream>>>((const uint*)net, starts, cnt, order, (uint*)seg);
        k_meanvec<<<16, 128, 0, stream>>>(meanB + ((i - 1) & 1) * 2048,
                                          wb0i, b0 + i * 128, wbsi, b1 + i * 128, rv0, rvS);
        float* mw = nullptr;
        if (i < NB - 1) {
            mw = meanB + (i & 1) * 2048;
            hipMemsetAsync(mw, 0, 2048 * 4, stream);
        }
        k_resblock<1><<<2048, 512, 0, stream>>>(
            nullptr, (const uint*)net, idx, seg, rv0, rvS, nullptr, nullptr,
            wb0i, nullptr, wb1i, nullptr, wbsi, net, mw);
    }

    // --- c = net @ Wc + bc (in-place, bf16) ---
    k_fcc<<<2048, 256, 0, stream>>>((const uint*)net, wb + 573440, bc, net);

    // --- per-plane segmented sum + transposed finalize ---
    for (int pl = 0; pl < 3; ++pl) {
        k_segsum<<<16384, 256, 0, stream>>>((const uint*)net, starts, cnt, order, sums, pl);
        k_fin<<<dim3(512, 16), 256, 0, stream>>>(sums, cnt, out, pl);
    }
}